// Round 3
// baseline (9909.618 us; speedup 1.0000x reference)
//
#include <hip/hip_runtime.h>
#include <hip/hip_fp16.h>

// ============================================================================
// LSTM_78176994722094: 2-layer LSTM (B=128, D_IN=128, T=1024, H=512) + fc head.
//
// R10 = R9 with fragment loads switched from inline-asm global_load_dwordx4
// to compiler-emitted __hip_atomic_load u64 AGENT pairs.
//
// R8/R9 forensics: BOTH hand-written sc encodings (sc0 sc1, sc1) force a
// device-scope probe-flush of dirty local-L2 exchange lines -> WRITE_SIZE
// 3.8MB -> 245MB (the full 256KB/round exchange volume written to the MALL
// every round) and ~700cy memory latency on the recurrence critical path.
// R7's staging loads -- __hip_atomic_load(RELAXED, AGENT) on the SAME dirty
// lines -- measured 3.8MB WRITE_SIZE at 4.1ms: the intrinsic's encoding
// provably hits dirty local-L2 lines WITHOUT flushing. R10 uses exactly that
// intrinsic for all exchange/xTw fragment loads. Compiler tracks its own
// loads (auto s_waitcnt at first use -> latency hides under the spin); the
// asm memory clobber after each spin pins load issue below the spin.
//
// Structure (unchanged from R8/R9): barrier-free per-wave pipeline.
//  1. B-fragments (h vectors) load DIRECTLY from the L2 exchange buffer in
//     MFMA fragment order (fragment order == buffer order). No hbuf, no LDS
//     staging, no bank conflicts, NO __syncthreads in the loop.
//  2. Per-WAVE flags, split per LAYER. flag0 set right after the L0 epilogue
//     (own vmcnt(0) drain, own flag) -> neighbors start round r+1 while this
//     wave still runs Wih1*h0, Whh1*h1 and the L1 epilogue. flag1 (set at
//     round end) has a full round of slack from the layer skew.
//  3. L0 critical chain split into 4 independent 8-deep MFMA accumulator
//     chains (hi/lo separate). x-refresh HBM load issued pre-spin, its
//     stores deferred past flag0.
//
// Stale-L1 safety for plain-ish loads (R7's proven mechanism): each CU reads
// 128KB/round of exchange+xTw through its 32KB L1 -> full thrash between a
// parity's write and its read (2-round gap). absmax drift >=1e-3 would be
// the staleness signature; R7 held 1.22e-4.
//
// Workspace (<4MB):
//   [0, 16KB)          sync: claim/mode/arrive + per-wave flags
//                        flag0: word 128  + c*128 + wcl   (8 clusters x 128)
//                        flag1: word 1280 + c*128 + wcl
//   [64KB, 576KB)      h exchange: [parity2][cluster8][layer2][b16][ch512] fp16
//   [640KB, 640KB+3MB) xTw: [slot3][cluster8][tau32][b16][d128] fp16
// ============================================================================

typedef _Float16 half8 __attribute__((ext_vector_type(8)));
typedef float f32x4 __attribute__((ext_vector_type(4)));
typedef unsigned long long u64;
typedef u64 u64x2 __attribute__((ext_vector_type(2)));

#define MFMA16(a, b, c) __builtin_amdgcn_mfma_f32_16x16x32_f16((a), (b), (c), 0, 0, 0)

#define WS_EXCH_OFF (64 << 10)
#define WS_XTW_OFF (640 << 10)
// sync word indices (u32) within ws base
#define SYNC_CLAIM 0     // 8 u32
#define SYNC_MODE 16     // 1 u32 (0=undecided, 1=fallback, 2=local)
#define SYNC_ARRIVE 24   // 1 u32
#define SYNC_FLAG0 128   // 8 clusters x 128 u32 (per-wave, layer 0)
#define SYNC_FLAG1 1280  // 8 clusters x 128 u32 (per-wave, layer 1)

__device__ __forceinline__ float sigf(float x) {
  return __builtin_amdgcn_rcpf(1.f + exp2f(-1.44269504f * x));
}
__device__ __forceinline__ float tanhf_(float x) {
  return 1.f - 2.f * __builtin_amdgcn_rcpf(1.f + exp2f(2.88539008f * x));
}
__device__ __forceinline__ unsigned short f2h(float x) {
  _Float16 h = (_Float16)x;  // RNE
  unsigned short b;
  __builtin_memcpy(&b, &h, 2);
  return b;
}
__device__ __forceinline__ u64 lda(const u64* p) {
  return __hip_atomic_load(p, __ATOMIC_RELAXED, __HIP_MEMORY_SCOPE_AGENT);
}
// 16B fragment via two compiler-emitted AGENT u64 loads (R7's proven
// encoding: hits dirty local-L2 lines without flushing them to the MALL).
__device__ __forceinline__ half8 ld_frag(const u64* p) {
  u64x2 t;
  t.x = __hip_atomic_load(p, __ATOMIC_RELAXED, __HIP_MEMORY_SCOPE_AGENT);
  t.y = __hip_atomic_load(p + 1, __ATOMIC_RELAXED, __HIP_MEMORY_SCOPE_AGENT);
  return __builtin_bit_cast(half8, t);
}

// split 8 fp32 weights -> hi fp16 + lo fp16 (lo = (w - hi) * 2^11)
__device__ __forceinline__ void cvt_split(const f32x4& a, const f32x4& b,
                                          half8& hi, half8& lo) {
#pragma unroll
  for (int i = 0; i < 4; ++i) {
    float w0 = a[i], w1 = b[i];
    _Float16 h0 = (_Float16)w0, h1 = (_Float16)w1;
    hi[i] = h0;
    hi[i + 4] = h1;
    lo[i] = (_Float16)((w0 - (float)h0) * 2048.0f);
    lo[i + 4] = (_Float16)((w1 - (float)h1) * 2048.0f);
  }
}
// scale a fragment by 2^-11 (exact exponent shift; v_pk_mul_f16)
__device__ __forceinline__ half8 hscale(half8 v) {
  half8 r;
#pragma unroll
  for (int i = 0; i < 8; ++i) r[i] = v[i] * (_Float16)4.8828125e-4f;
  return r;
}

// ---------------------------------------------------------------------------
// Prepass: fill xTw window 0 (t=0..31) slot 0, zero sync area (16KB) and out.
// ---------------------------------------------------------------------------
__global__ void __launch_bounds__(256) prep_kernel(const float* __restrict__ x,
                                                   _Float16* __restrict__ xTw,
                                                   unsigned* __restrict__ sync,
                                                   float* __restrict__ out) {
  const int bid = blockIdx.x;  // 128 = 8c * 16b
  const int c = bid >> 4, b16 = bid & 15;
  const int tid = threadIdx.x;
  if (bid == 0) {
#pragma unroll
    for (int i = 0; i < 16; ++i) sync[i * 256 + tid] = 0;  // 16KB sync area
    out[tid] = 0.f;  // out_size = B*OUT = 256
  }
  const int d = tid & 127, th = tid >> 7;  // th: tau half (0/1)
  const float* src = x + ((size_t)(c * 16 + b16) * 128 + d) * 1024 + th * 16;
  _Float16* dst = xTw + ((size_t)c * 32 + th * 16) * (16 * 128) + b16 * 128 + d;
#pragma unroll
  for (int i = 0; i < 16; ++i) dst[(size_t)i * (16 * 128)] = (_Float16)src[i];
}

// ---------------------------------------------------------------------------
// Persistent scan kernel. MFMA 16x16x32 f16 layouts (verified R1-R9):
//   A[m=lane&15][k=(lane>>4)*8+j], B[k][n=lane&15], D[m=(lane>>4)*4+reg][n].
// ---------------------------------------------------------------------------
__global__ void __launch_bounds__(256, 1) lstm_scan(
    const float* __restrict__ Whh0, const float* __restrict__ bih0,
    const float* __restrict__ bhh0, const float* __restrict__ Wih1,
    const float* __restrict__ Whh1, const float* __restrict__ bih1,
    const float* __restrict__ bhh1, const float* __restrict__ fcW,
    const float* __restrict__ fcb, const float* __restrict__ Wih0,
    const float* __restrict__ x, unsigned* __restrict__ sync,
    unsigned short* __restrict__ exch, _Float16* __restrict__ xTw,
    float* __restrict__ out) {
  __shared__ unsigned s_bcast[2];

  const int tid = threadIdx.x;
  const int wave = tid >> 6;
  const int lane = tid & 63;
  const int q = lane >> 4;
  const int bb = lane & 15;

  // ---- startup: XCD discovery + slot claim + grid barrier + mode decide ----
  unsigned xcc;
  asm("s_getreg_b32 %0, hwreg(HW_REG_XCC_ID)" : "=s"(xcc));
  xcc &= 7;
  unsigned* claim = sync + SYNC_CLAIM;
  unsigned* modew = sync + SYNC_MODE;
  unsigned* arrive = sync + SYNC_ARRIVE;
  if (tid == 0) {
    unsigned idx = __hip_atomic_fetch_add(claim + xcc, 1u, __ATOMIC_RELAXED,
                                          __HIP_MEMORY_SCOPE_AGENT);
    // (idx>>31)==0; data-dependency forces the claim RMW to complete first
    unsigned ord = __hip_atomic_fetch_add(arrive, 1u + (idx >> 31),
                                          __ATOMIC_RELAXED,
                                          __HIP_MEMORY_SCOPE_AGENT);
    if (ord == 255u) {  // last arriver decides for everyone
      unsigned ok = 1;
#pragma unroll
      for (int i = 0; i < 8; ++i)
        ok &= (__hip_atomic_load(claim + i, __ATOMIC_RELAXED,
                                 __HIP_MEMORY_SCOPE_AGENT) == 32u);
      __hip_atomic_store(modew, ok ? 2u : 1u, __ATOMIC_RELAXED,
                         __HIP_MEMORY_SCOPE_AGENT);
    }
    unsigned mv = 0;
    int guard = 0;
    for (;;) {
      mv = __hip_atomic_load(modew, __ATOMIC_RELAXED, __HIP_MEMORY_SCOPE_AGENT);
      if (mv != 0u) break;
      if (++guard > (1 << 18)) { mv = 1u; break; }
    }
    s_bcast[0] = mv;
    s_bcast[1] = idx;
  }
  __syncthreads();
  const bool loc = (s_bcast[0] == 2u);
  const int c = loc ? (int)xcc : (blockIdx.x >> 5);
  const int wg = loc ? (int)s_bcast[1] : (blockIdx.x & 31);

  const int wcl = wg * 4 + wave;  // wave id in cluster: 0..127
  const int chbase = wcl * 4;     // this wave's 4 hidden channels
  const int m = lane & 15;        // A-fragment row id for this lane
  const int arow = (m & 3) * 512 + chbase + (m >> 2);  // i,f,g,o gate order
  unsigned short* xtw16 = (unsigned short*)xTw;
  const u64* exch64c = (const u64*)exch;

  // ---- one-time: weight A-fragments (hi for all; lo for Whh0/Wih1/Wih0) ----
  half8 fW0[16], fW0lo[16], fW1i[16], fW1ilo[16], fW1h[16], fX[4], fXlo[4];
  {
    const float* p0 = Whh0 + (size_t)arow * 512 + q * 8;
    const float* p1 = Wih1 + (size_t)arow * 512 + q * 8;
    const float* p2 = Whh1 + (size_t)arow * 512 + q * 8;
#pragma unroll
    for (int kt = 0; kt < 16; ++kt) {
      f32x4 a0 = *(const f32x4*)(p0 + kt * 32), b0 = *(const f32x4*)(p0 + kt * 32 + 4);
      cvt_split(a0, b0, fW0[kt], fW0lo[kt]);
      f32x4 a1 = *(const f32x4*)(p1 + kt * 32), b1 = *(const f32x4*)(p1 + kt * 32 + 4);
      cvt_split(a1, b1, fW1i[kt], fW1ilo[kt]);
      f32x4 a2 = *(const f32x4*)(p2 + kt * 32), b2 = *(const f32x4*)(p2 + kt * 32 + 4);
      half8 dummy;
      cvt_split(a2, b2, fW1h[kt], dummy);  // hi only
    }
    const float* p3 = Wih0 + (size_t)arow * 128 + q * 8;
#pragma unroll
    for (int kt = 0; kt < 4; ++kt) {
      f32x4 a3 = *(const f32x4*)(p3 + kt * 32), b3 = *(const f32x4*)(p3 + kt * 32 + 4);
      cvt_split(a3, b3, fX[kt], fXlo[kt]);
    }
  }

  float b0v[4], b1v[4];
#pragma unroll
  for (int g = 0; g < 4; ++g) {
    int rrow = g * 512 + chbase + q;
    b0v[g] = bih0[rrow] + bhh0[rrow];
    b1v[g] = bih1[rrow] + bhh1[rrow];
  }
  const int ch = chbase + q;
  const float fcw0 = fcW[ch], fcw1 = fcW[512 + ch];

  unsigned* flag0 = sync + SYNC_FLAG0 + c * 128;
  unsigned* flag1 = sync + SYNC_FLAG1 + c * 128;
  const u64* spin0p = (const u64*)flag0 + lane;  // lane polls 2 wave-flags
  const u64* spin1p = (const u64*)flag1 + lane;

  float c0 = 0.f, c1 = 0.f;
  const int T = 1024;
  for (int r = 0; r <= T; ++r) {
    const bool L0 = (r < T);
    const bool L1 = (r > 0);
    const bool L1h = (r > 1);
    const bool doref = (wave == 2 && r < 992 && (r & 3) == 0);

    // ---- x refresh LOAD only (stores deferred past flag0). float4 read
    //      keeps HBM line amplification at 4x. ----
    f32x4 xv4;
    int sw = 0, rw = 0, xb = 0, xd = 0;
    if (doref) {
      const int wnext = (r >> 5) + 1;
      sw = wnext % 3; rw = r & 31;
      xb = wg >> 1; xd = (wg & 1) * 64 + lane;
      xv4 = *(const f32x4*)(x + ((size_t)(c * 16 + xb) * 128 + xd) * 1024 +
                            wnext * 32 + rw);
    }

    // ---- x fragments for t=r, issued BEFORE the spin (slot written >=32
    //      rounds ago -> long drained to the local L2; waitcnt lands at
    //      first use, after the spin) ----
    half8 xf[4];
    if (L0) {
      const int s = (r >> 5) % 3, tau = r & 31;
      const u64* xpq = (const u64*)xtw16 +
                       (((size_t)(s * 8 + c) * 32 + tau) * 16 + bb) * 32 + q * 2;
#pragma unroll
      for (int kt = 0; kt < 4; ++kt) xf[kt] = ld_frag(xpq + kt * 8);
    }

    // ---- spin0: h0[r-1] published by all 128 waves of the cluster ----
    if (L1) {
      int guard = 0;
      for (;;) {
        u64 f = lda(spin0p);
        bool ok = ((unsigned)f >= (unsigned)r) &&
                  ((unsigned)(f >> 32) >= (unsigned)r);
        if (__ballot(ok) == ~0ull) break;
        if (++guard > 2048) break;  // diagnostic fail-fast, never hangs
      }
      asm volatile("" ::: "memory");  // keep fragment loads below the spin
    }

    // ---- h0[r-1] B-fragments, direct AGENT u64 pairs from the L2 exchange ----
    const int p = (r - 1) & 1;
    half8 hA[8], hB[8];
    if (L1) {
      const u64* h0p =
          exch64c + ((size_t)p * 8 + c) * 4096 + (size_t)bb * 128 + q * 2;
#pragma unroll
      for (int kt = 0; kt < 8; ++kt) {
        hA[kt] = ld_frag(h0p + kt * 8);
        hB[kt] = ld_frag(h0p + 64 + kt * 8);
      }
    }

    // ---- L0 critical chain: 4 independent 8-deep MFMA chains + x chain ----
    if (L0) {
      f32x4 accX = {b0v[0], b0v[1], b0v[2], b0v[3]};
#pragma unroll
      for (int kt = 0; kt < 4; ++kt) {
        accX = MFMA16(fX[kt], xf[kt], accX);
        accX = MFMA16(fXlo[kt], hscale(xf[kt]), accX);
      }
      f32x4 a0 = {0.f, 0.f, 0.f, 0.f};
      f32x4 a0b = a0, a0l = a0, a0bl = a0;
      if (L1) {
#pragma unroll
        for (int kt = 0; kt < 8; ++kt) {
          a0 = MFMA16(fW0[kt], hA[kt], a0);
          a0b = MFMA16(fW0[kt + 8], hB[kt], a0b);
          a0l = MFMA16(fW0lo[kt], hscale(hA[kt]), a0l);
          a0bl = MFMA16(fW0lo[kt + 8], hscale(hB[kt]), a0bl);
        }
      }
      f32x4 g0 = accX + ((a0 + a0b) + (a0l + a0bl));
      float gi = sigf(g0.x), gf = sigf(g0.y), gg = tanhf_(g0.z), go = sigf(g0.w);
      c0 = gf * c0 + gi * gg;
      float h0v = go * tanhf_(c0);
      size_t idx = (((size_t)(r & 1) * 8 + c) * 32 + bb) * 512 + ch;
      if (loc)
        exch[idx] = f2h(h0v);  // plain -> dirty line in local L2
      else
        __hip_atomic_store(exch + idx, f2h(h0v), __ATOMIC_RELAXED,
                           __HIP_MEMORY_SCOPE_AGENT);
      asm volatile("s_waitcnt vmcnt(0)" ::: "memory");  // h0 store complete
      if (lane == 0) {
        if (loc)
          __hip_atomic_store(flag0 + wcl, (unsigned)(r + 1), __ATOMIC_RELAXED,
                             __HIP_MEMORY_SCOPE_WORKGROUP);
        else
          __hip_atomic_store(flag0 + wcl, (unsigned)(r + 1), __ATOMIC_RELAXED,
                             __HIP_MEMORY_SCOPE_AGENT);
      }
    }

    // ---- x refresh stores (off the h0 critical path) ----
    if (doref) {
#pragma unroll
      for (int j = 0; j < 4; ++j) {
        size_t xidx =
            (((size_t)(sw * 8 + c) * 32 + rw + j) * 16 + xb) * 128 + xd;
        if (loc)
          xtw16[xidx] = f2h(xv4[j]);
        else
          __hip_atomic_store(xtw16 + xidx, f2h(xv4[j]), __ATOMIC_RELAXED,
                             __HIP_MEMORY_SCOPE_AGENT);
      }
    }

    // ---- L1 input chain (Wih1 * h0[r-1]) -- after flag0, reuses hA/hB ----
    f32x4 a1 = {b1v[0], b1v[1], b1v[2], b1v[3]};
    f32x4 a1b = {0.f, 0.f, 0.f, 0.f};
    f32x4 a1c = a1b, a1d = a1b;
    if (L1) {
#pragma unroll
      for (int kt = 0; kt < 8; ++kt) {
        half8 hAs = hscale(hA[kt]), hBs = hscale(hB[kt]);
        a1 = MFMA16(fW1i[kt], hA[kt], a1);
        a1b = MFMA16(fW1i[kt + 8], hB[kt], a1b);
        a1 = MFMA16(fW1ilo[kt], hAs, a1);
        a1b = MFMA16(fW1ilo[kt + 8], hBs, a1b);
      }
    }

    // ---- L1 recurrent chain (Whh1 * h1[r-2]); flag1 has a round of slack ----
    if (L1h) {
      int guard = 0;
      for (;;) {
        u64 f = lda(spin1p);
        bool ok = ((unsigned)f >= (unsigned)r) &&
                  ((unsigned)(f >> 32) >= (unsigned)r);
        if (__ballot(ok) == ~0ull) break;
        if (++guard > 2048) break;
      }
      asm volatile("" ::: "memory");
      const u64* h1p = exch64c + ((size_t)p * 8 + c) * 4096 +
                       (size_t)(16 + bb) * 128 + q * 2;
      half8 hC[8], hD[8];
#pragma unroll
      for (int kt = 0; kt < 8; ++kt) {
        hC[kt] = ld_frag(h1p + kt * 8);
        hD[kt] = ld_frag(h1p + 64 + kt * 8);
      }
#pragma unroll
      for (int kt = 0; kt < 8; ++kt) {
        a1c = MFMA16(fW1h[kt], hC[kt], a1c);
        a1d = MFMA16(fW1h[kt + 8], hD[kt], a1d);
      }
    }

    if (L1) {
      f32x4 g1 = (a1 + a1b) + (a1c + a1d);
      float gi = sigf(g1.x), gf = sigf(g1.y), gg = tanhf_(g1.z), go = sigf(g1.w);
      c1 = gf * c1 + gi * gg;
      float h1v = go * tanhf_(c1);
      if (r == T) {
        // fc head (out zeroed by prep_kernel each call)
        float s0 = h1v * fcw0, s1 = h1v * fcw1;
        s0 += __shfl_xor(s0, 16); s0 += __shfl_xor(s0, 32);
        s1 += __shfl_xor(s1, 16); s1 += __shfl_xor(s1, 32);
        if (q == 0) {
          atomicAdd(out + (size_t)(c * 16 + bb) * 2 + 0, s0);
          atomicAdd(out + (size_t)(c * 16 + bb) * 2 + 1, s1);
        }
        if (wcl == 0 && lane < 32)
          atomicAdd(out + (size_t)(c * 16 + (lane & 15)) * 2 + (lane >> 4),
                    fcb[lane >> 4]);
      } else {
        size_t idx = (((size_t)(r & 1) * 8 + c) * 32 + 16 + bb) * 512 + ch;
        if (loc)
          exch[idx] = f2h(h1v);
        else
          __hip_atomic_store(exch + idx, f2h(h1v), __ATOMIC_RELAXED,
                             __HIP_MEMORY_SCOPE_AGENT);
        asm volatile("s_waitcnt vmcnt(0)" ::: "memory");  // h1 store complete
        if (lane == 0) {
          if (loc)
            __hip_atomic_store(flag1 + wcl, (unsigned)(r + 1), __ATOMIC_RELAXED,
                               __HIP_MEMORY_SCOPE_WORKGROUP);
          else
            __hip_atomic_store(flag1 + wcl, (unsigned)(r + 1), __ATOMIC_RELAXED,
                               __HIP_MEMORY_SCOPE_AGENT);
        }
      }
    }
  }
}

extern "C" void kernel_launch(void* const* d_in, const int* in_sizes, int n_in,
                              void* d_out, int out_size, void* d_ws,
                              size_t ws_size, hipStream_t stream) {
  const float* x = (const float*)d_in[0];
  const float* Wih0 = (const float*)d_in[1];
  const float* Whh0 = (const float*)d_in[2];
  const float* bih0 = (const float*)d_in[3];
  const float* bhh0 = (const float*)d_in[4];
  const float* Wih1 = (const float*)d_in[5];
  const float* Whh1 = (const float*)d_in[6];
  const float* bih1 = (const float*)d_in[7];
  const float* bhh1 = (const float*)d_in[8];
  const float* fcW = (const float*)d_in[9];
  const float* fcb = (const float*)d_in[10];

  char* ws = (char*)d_ws;  // uses < 4MB total
  unsigned* sync = (unsigned*)ws;
  unsigned short* exch = (unsigned short*)(ws + WS_EXCH_OFF);
  _Float16* xTw = (_Float16*)(ws + WS_XTW_OFF);
  float* out = (float*)d_out;

  prep_kernel<<<dim3(128), dim3(256), 0, stream>>>(x, xTw, sync, out);
  lstm_scan<<<dim3(256), dim3(256), 0, stream>>>(Whh0, bih0, bhh0, Wih1, Whh1,
                                                 bih1, bhh1, fcW, fcb, Wih0, x,
                                                 sync, exch, xTw, out);
}

// Round 5
// 4903.680 us; speedup vs baseline: 2.0209x; 2.0209x over previous
//
#include <hip/hip_runtime.h>
#include <hip/hip_fp16.h>

// ============================================================================
// LSTM_78176994722094: 2-layer LSTM (B=128, D_IN=128, T=1024, H=512) + fc head.
//
// R12 = R11 resubmitted byte-identical (R4 bench was an infra/container
// failure: no dispatch, no counters; R11 cannot hang -- all spins guarded,
// barriers unconditional).
//
// R11 = R7's proven skeleton + split per-layer flags (the one R8 idea that
// was never actually falsified).
//
// Forensic ledger:
//  R7  (4.1ms): LDS staging, 2 barriers, ONE end-of-round flag. ~9.7Kcy/round
//      vs ~3Kcy serial work -> ~6Kcy/round of convoy waiting (every consumer
//      waits for the slowest producer's FULL round incl. L1 tail; no slack).
//  R8/R9 (7.9ms): direct per-wave fragment loads with hand-rolled sc bits ->
//      sc0sc1/sc1 loads probe-FLUSH dirty local-L2 lines (WRITE_SIZE 3.8MB ->
//      245MB, MALL latency on the recurrence path).
//  R10 (9.9ms): same structure, compiler atomic loads -> traffic clean but
//      4 waves x 36KB = 144KB/CU/round of 8B-granular L2 reads (4x the staged
//      volume) = L2-BW infeasible. LDS staging is REQUIRED dedup, not overhead.
//
// R11 changes vs R7 (everything else byte-equivalent):
//  1. Two flag arrays, PER-WAVE (128/cluster/layer; u64-pair polling, proven
//     R8-R10). flag0 set right after the h0 publish (mid-round) -> consumers'
//     phase-A spin finds it ~half a round early. flag1 set at round end; its
//     consumers (phase B) spin ~mid-round -> half-round slack absorbs jitter.
//  2. Round split into two staged phases:
//       A: spin0 -> stage h0(16KB) -> barrier -> accX+Whh0 chains (40 MFMA)
//          -> h0 epilogue -> publish h0 -> vmcnt(0) -> flag0
//       B: Wih1*h0 chains (32 MFMA, re-read LDS) -> spin1 -> stage h1(16KB)
//          -> barrier -> Whh1 chains (16 MFMA) -> h1 epilogue -> publish h1
//          -> vmcnt(0) -> flag1
//     Still exactly 2 barriers/round. LDS reuse safety: stage-h0(r) is after
//     barrier-B(r-1) (all waves done reading hbuf[0]); stage-h1(r) is after
//     barrier-A(r) (all waves done with L1h(r-1)).
//
// Workspace (<4MB):
//   [0, 16KB)          sync: flags + claim/mode/arrive (all zeroed by prep)
//                        claim@1024, mode@1040, arrive@1056
//                        flag0: word 1280 + c*128 + wcl
//                        flag1: word 2304 + c*128 + wcl
//   [64KB, 576KB)      h exchange: [parity2][cluster8][layer2][b16][ch512] fp16
//   [640KB, 640KB+3MB) xTw: [slot3][cluster8][tau32][b16][d128] fp16
// ============================================================================

typedef _Float16 half8 __attribute__((ext_vector_type(8)));
typedef float f32x4 __attribute__((ext_vector_type(4)));
typedef unsigned long long u64;
typedef u64 u64x2 __attribute__((ext_vector_type(2)));

#define MFMA16(a, b, c) __builtin_amdgcn_mfma_f32_16x16x32_f16((a), (b), (c), 0, 0, 0)

#define WS_EXCH_OFF (64 << 10)
#define WS_XTW_OFF (640 << 10)
// sync word indices (u32) within ws base (prep zeroes words [0,4096))
#define SYNC_CLAIM 1024   // 8 u32
#define SYNC_MODE 1040    // 1 u32 (0=undecided, 1=fallback, 2=local)
#define SYNC_ARRIVE 1056  // 1 u32
#define SYNC_FLAG0 1280   // 8 clusters x 128 u32 (per-wave, layer 0)
#define SYNC_FLAG1 2304   // 8 clusters x 128 u32 (per-wave, layer 1)

__device__ __forceinline__ float sigf(float x) {
  return __builtin_amdgcn_rcpf(1.f + exp2f(-1.44269504f * x));
}
__device__ __forceinline__ float tanhf_(float x) {
  return 1.f - 2.f * __builtin_amdgcn_rcpf(1.f + exp2f(2.88539008f * x));
}
__device__ __forceinline__ unsigned short f2h(float x) {
  _Float16 h = (_Float16)x;  // RNE
  unsigned short b;
  __builtin_memcpy(&b, &h, 2);
  return b;
}
__device__ __forceinline__ u64 lda(const u64* p) {
  return __hip_atomic_load(p, __ATOMIC_RELAXED, __HIP_MEMORY_SCOPE_AGENT);
}

// split 8 fp32 weights -> hi fp16 + lo fp16 (lo = (w - hi) * 2^11)
__device__ __forceinline__ void cvt_split(const f32x4& a, const f32x4& b,
                                          half8& hi, half8& lo) {
#pragma unroll
  for (int i = 0; i < 4; ++i) {
    float w0 = a[i], w1 = b[i];
    _Float16 h0 = (_Float16)w0, h1 = (_Float16)w1;
    hi[i] = h0;
    hi[i + 4] = h1;
    lo[i] = (_Float16)((w0 - (float)h0) * 2048.0f);
    lo[i + 4] = (_Float16)((w1 - (float)h1) * 2048.0f);
  }
}
// scale a fragment by 2^-11 (exact exponent shift; v_pk_mul_f16)
__device__ __forceinline__ half8 hscale(half8 v) {
  half8 r;
#pragma unroll
  for (int i = 0; i < 8; ++i) r[i] = v[i] * (_Float16)4.8828125e-4f;
  return r;
}

// ---------------------------------------------------------------------------
// Prepass: fill xTw window 0 (t=0..31) slot 0, zero sync area (16KB) and out.
// ---------------------------------------------------------------------------
__global__ void __launch_bounds__(256) prep_kernel(const float* __restrict__ x,
                                                   _Float16* __restrict__ xTw,
                                                   unsigned* __restrict__ sync,
                                                   float* __restrict__ out) {
  const int bid = blockIdx.x;  // 128 = 8c * 16b
  const int c = bid >> 4, b16 = bid & 15;
  const int tid = threadIdx.x;
  if (bid == 0) {
#pragma unroll
    for (int i = 0; i < 16; ++i) sync[i * 256 + tid] = 0;  // 16KB sync area
    out[tid] = 0.f;  // out_size = B*OUT = 256
  }
  const int d = tid & 127, th = tid >> 7;  // th: tau half (0/1)
  const float* src = x + ((size_t)(c * 16 + b16) * 128 + d) * 1024 + th * 16;
  _Float16* dst = xTw + ((size_t)c * 32 + th * 16) * (16 * 128) + b16 * 128 + d;
#pragma unroll
  for (int i = 0; i < 16; ++i) dst[(size_t)i * (16 * 128)] = (_Float16)src[i];
}

// ---------------------------------------------------------------------------
// Persistent scan kernel. MFMA 16x16x32 f16 layouts (verified R1-R10):
//   A[m=lane&15][k=(lane>>4)*8+j], B[k][n=lane&15], D[m=(lane>>4)*4+reg][n].
// ---------------------------------------------------------------------------
__global__ void __launch_bounds__(256, 1) lstm_scan(
    const float* __restrict__ Whh0, const float* __restrict__ bih0,
    const float* __restrict__ bhh0, const float* __restrict__ Wih1,
    const float* __restrict__ Whh1, const float* __restrict__ bih1,
    const float* __restrict__ bhh1, const float* __restrict__ fcW,
    const float* __restrict__ fcb, const float* __restrict__ Wih0,
    const float* __restrict__ x, unsigned* __restrict__ sync,
    unsigned short* __restrict__ exch, _Float16* __restrict__ xTw,
    float* __restrict__ out) {
  __shared__ __align__(16) _Float16 hbuf[2][16][520];  // [layer][b16][ch+pad]
  __shared__ unsigned s_bcast[2];

  const int tid = threadIdx.x;
  const int wave = tid >> 6;
  const int lane = tid & 63;
  const int q = lane >> 4;
  const int bb = lane & 15;

  // ---- startup: XCD discovery + slot claim + grid barrier + mode decide ----
  unsigned xcc;
  asm("s_getreg_b32 %0, hwreg(HW_REG_XCC_ID)" : "=s"(xcc));
  xcc &= 7;
  unsigned* claim = sync + SYNC_CLAIM;
  unsigned* modew = sync + SYNC_MODE;
  unsigned* arrive = sync + SYNC_ARRIVE;
  if (tid == 0) {
    unsigned idx = __hip_atomic_fetch_add(claim + xcc, 1u, __ATOMIC_RELAXED,
                                          __HIP_MEMORY_SCOPE_AGENT);
    // (idx>>31)==0; data-dependency forces the claim RMW to complete first
    unsigned ord = __hip_atomic_fetch_add(arrive, 1u + (idx >> 31),
                                          __ATOMIC_RELAXED,
                                          __HIP_MEMORY_SCOPE_AGENT);
    if (ord == 255u) {  // last arriver decides for everyone
      unsigned ok = 1;
#pragma unroll
      for (int i = 0; i < 8; ++i)
        ok &= (__hip_atomic_load(claim + i, __ATOMIC_RELAXED,
                                 __HIP_MEMORY_SCOPE_AGENT) == 32u);
      __hip_atomic_store(modew, ok ? 2u : 1u, __ATOMIC_RELAXED,
                         __HIP_MEMORY_SCOPE_AGENT);
    }
    unsigned mv = 0;
    int guard = 0;
    for (;;) {
      mv = __hip_atomic_load(modew, __ATOMIC_RELAXED, __HIP_MEMORY_SCOPE_AGENT);
      if (mv != 0u) break;
      if (++guard > (1 << 18)) { mv = 1u; break; }
    }
    s_bcast[0] = mv;
    s_bcast[1] = idx;
  }
  __syncthreads();
  const bool loc = (s_bcast[0] == 2u);
  const int c = loc ? (int)xcc : (blockIdx.x >> 5);
  const int wg = loc ? (int)s_bcast[1] : (blockIdx.x & 31);

  const int wcl = wg * 4 + wave;  // wave id in cluster: 0..127
  const int chbase = wcl * 4;     // this wave's 4 hidden channels
  const int m = lane & 15;        // A-fragment row id for this lane
  const int arow = (m & 3) * 512 + chbase + (m >> 2);  // i,f,g,o gate order
  unsigned short* xtw16 = (unsigned short*)xTw;
  const u64* exch64c = (const u64*)exch;

  // ---- one-time: weight A-fragments (hi for all; lo for Whh0/Wih1/Wih0) ----
  half8 fW0[16], fW0lo[16], fW1i[16], fW1ilo[16], fW1h[16], fX[4], fXlo[4];
  {
    const float* p0 = Whh0 + (size_t)arow * 512 + q * 8;
    const float* p1 = Wih1 + (size_t)arow * 512 + q * 8;
    const float* p2 = Whh1 + (size_t)arow * 512 + q * 8;
#pragma unroll
    for (int kt = 0; kt < 16; ++kt) {
      f32x4 a0 = *(const f32x4*)(p0 + kt * 32), b0 = *(const f32x4*)(p0 + kt * 32 + 4);
      cvt_split(a0, b0, fW0[kt], fW0lo[kt]);
      f32x4 a1 = *(const f32x4*)(p1 + kt * 32), b1 = *(const f32x4*)(p1 + kt * 32 + 4);
      cvt_split(a1, b1, fW1i[kt], fW1ilo[kt]);
      f32x4 a2 = *(const f32x4*)(p2 + kt * 32), b2 = *(const f32x4*)(p2 + kt * 32 + 4);
      half8 dummy;
      cvt_split(a2, b2, fW1h[kt], dummy);  // hi only
    }
    const float* p3 = Wih0 + (size_t)arow * 128 + q * 8;
#pragma unroll
    for (int kt = 0; kt < 4; ++kt) {
      f32x4 a3 = *(const f32x4*)(p3 + kt * 32), b3 = *(const f32x4*)(p3 + kt * 32 + 4);
      cvt_split(a3, b3, fX[kt], fXlo[kt]);
    }
  }

  float b0v[4], b1v[4];
#pragma unroll
  for (int g = 0; g < 4; ++g) {
    int rrow = g * 512 + chbase + q;
    b0v[g] = bih0[rrow] + bhh0[rrow];
    b1v[g] = bih1[rrow] + bhh1[rrow];
  }
  const int ch = chbase + q;
  const float fcw0 = fcW[ch], fcw1 = fcW[512 + ch];

  unsigned* flag0 = sync + SYNC_FLAG0 + c * 128;
  unsigned* flag1 = sync + SYNC_FLAG1 + c * 128;
  const u64* spin0p = (const u64*)flag0 + lane;  // lane polls 2 wave-flags
  const u64* spin1p = (const u64*)flag1 + lane;

  float c0 = 0.f, c1 = 0.f;
  const int T = 1024;
  for (int r = 0; r <= T; ++r) {
    const bool L0 = (r < T);
    const bool L1 = (r > 0);
    const bool L1h = (r > 1);
    const bool doref = (wave == 2 && r < 992 && (r & 3) == 0);
    const int p = (r - 1) & 1;

    // ---- x refresh LOAD only (stores deferred past flag0). float4 read
    //      keeps HBM line amplification at 4x. ----
    f32x4 xv4;
    int sw = 0, rw = 0, xb = 0, xd = 0;
    if (doref) {
      const int wnext = (r >> 5) + 1;
      sw = wnext % 3; rw = r & 31;
      xb = wg >> 1; xd = (wg & 1) * 64 + lane;
      xv4 = *(const f32x4*)(x + ((size_t)(c * 16 + xb) * 128 + xd) * 1024 +
                            wnext * 32 + rw);
    }

    // ---- x fragments for t=r, issued BEFORE the spin (slot written >=32
    //      rounds ago -> long drained to the local L2) ----
    half8 xf[4];
    if (L0) {
      const int s = (r >> 5) % 3, tau = r & 31;
      const u64* xp =
          (const u64*)xtw16 + (((size_t)(s * 8 + c) * 32 + tau) * 16 + bb) * 32;
#pragma unroll
      for (int kt = 0; kt < 4; ++kt) {
        u64x2 t2;
        t2.x = lda(xp + kt * 8 + q * 2);
        t2.y = lda(xp + kt * 8 + q * 2 + 1);
        xf[kt] = __builtin_bit_cast(half8, t2);
      }
    }

    // ================= PHASE A: layer-0 recurrence =================
    // spin0: h0[r-1] flags were set MID-round r-1 -> typically already set.
    if (L1) {
      int guard = 0;
      for (;;) {
        u64 f = lda(spin0p);
        bool ok = ((unsigned)f >= (unsigned)r) &&
                  ((unsigned)(f >> 32) >= (unsigned)r);
        if (__ballot(ok) == ~0ull) break;
        if (++guard > 4096) break;  // diagnostic fail-fast, never hangs
      }
      asm volatile("" ::: "memory");  // keep staging loads below the spin
      // stage h0[r-1] (16KB) into LDS (agent u64 loads hit dirty local-L2)
      const u64* src = exch64c + ((size_t)p * 8 + c) * 4096 + tid;
      u64 v[8];
#pragma unroll
      for (int i = 0; i < 8; ++i) v[i] = lda(src + i * 256);
#pragma unroll
      for (int i = 0; i < 8; ++i) {
        int f = i * 256 + tid;
        *((u64*)(&hbuf[0][f >> 7][0]) + (f & 127)) = v[i];
      }
    }
    __syncthreads();  // barrier A: h0 staging visible

    if (L0) {
      f32x4 accX = {b0v[0], b0v[1], b0v[2], b0v[3]};
#pragma unroll
      for (int kt = 0; kt < 4; ++kt) {
        accX = MFMA16(fX[kt], xf[kt], accX);
        accX = MFMA16(fXlo[kt], hscale(xf[kt]), accX);
      }
      f32x4 a0 = {0.f, 0.f, 0.f, 0.f};
      f32x4 a0b = a0, a0l = a0, a0bl = a0;
      if (L1) {
#pragma unroll
        for (int kt = 0; kt < 8; ++kt) {
          half8 hA = *(const half8*)(&hbuf[0][bb][kt * 32 + q * 8]);
          half8 hB = *(const half8*)(&hbuf[0][bb][(kt + 8) * 32 + q * 8]);
          a0 = MFMA16(fW0[kt], hA, a0);
          a0b = MFMA16(fW0[kt + 8], hB, a0b);
          a0l = MFMA16(fW0lo[kt], hscale(hA), a0l);
          a0bl = MFMA16(fW0lo[kt + 8], hscale(hB), a0bl);
        }
      }
      f32x4 g0 = accX + ((a0 + a0b) + (a0l + a0bl));
      float gi = sigf(g0.x), gf = sigf(g0.y), gg = tanhf_(g0.z), go = sigf(g0.w);
      c0 = gf * c0 + gi * gg;
      float h0v = go * tanhf_(c0);
      size_t idx = (((size_t)(r & 1) * 8 + c) * 32 + bb) * 512 + ch;
      if (loc)
        exch[idx] = f2h(h0v);  // plain -> dirty line in local L2
      else
        __hip_atomic_store(exch + idx, f2h(h0v), __ATOMIC_RELAXED,
                           __HIP_MEMORY_SCOPE_AGENT);
      asm volatile("s_waitcnt vmcnt(0)" ::: "memory");  // h0 store complete
      if (lane == 0) {
        if (loc)
          __hip_atomic_store(flag0 + wcl, (unsigned)(r + 1), __ATOMIC_RELAXED,
                             __HIP_MEMORY_SCOPE_WORKGROUP);
        else
          __hip_atomic_store(flag0 + wcl, (unsigned)(r + 1), __ATOMIC_RELAXED,
                             __HIP_MEMORY_SCOPE_AGENT);
      }
    }

    // ---- x refresh stores (off the h0 critical path) ----
    if (doref) {
#pragma unroll
      for (int j = 0; j < 4; ++j) {
        size_t xidx =
            (((size_t)(sw * 8 + c) * 32 + rw + j) * 16 + xb) * 128 + xd;
        if (loc)
          xtw16[xidx] = f2h(xv4[j]);
        else
          __hip_atomic_store(xtw16 + xidx, f2h(xv4[j]), __ATOMIC_RELAXED,
                             __HIP_MEMORY_SCOPE_AGENT);
      }
    }

    // ================= PHASE B: layer-1 (off the critical path) =======
    // L1 input chain (Wih1 * h0[r-1]) -- re-reads hbuf[0] (still valid:
    // stage-h0(r+1) happens only after barrier B below).
    f32x4 a1 = {b1v[0], b1v[1], b1v[2], b1v[3]};
    f32x4 a1b = {0.f, 0.f, 0.f, 0.f};
    f32x4 a1c = a1b, a1d = a1b;
    if (L1) {
#pragma unroll
      for (int kt = 0; kt < 8; ++kt) {
        half8 hA = *(const half8*)(&hbuf[0][bb][kt * 32 + q * 8]);
        half8 hB = *(const half8*)(&hbuf[0][bb][(kt + 8) * 32 + q * 8]);
        a1 = MFMA16(fW1i[kt], hA, a1);
        a1b = MFMA16(fW1i[kt + 8], hB, a1b);
        a1 = MFMA16(fW1ilo[kt], hscale(hA), a1);
        a1b = MFMA16(fW1ilo[kt + 8], hscale(hB), a1b);
      }
    }

    // spin1: flag1(>=r) was set at END of round r-1; we poll ~mid-round r
    // -> half a round of slack absorbs producer jitter.
    if (L1h) {
      int guard = 0;
      for (;;) {
        u64 f = lda(spin1p);
        bool ok = ((unsigned)f >= (unsigned)r) &&
                  ((unsigned)(f >> 32) >= (unsigned)r);
        if (__ballot(ok) == ~0ull) break;
        if (++guard > 4096) break;
      }
      asm volatile("" ::: "memory");
      // stage h1[r-2] (16KB) into hbuf[1]
      const u64* src = exch64c + ((size_t)p * 8 + c) * 4096 + 2048 + tid;
      u64 v[8];
#pragma unroll
      for (int i = 0; i < 8; ++i) v[i] = lda(src + i * 256);
#pragma unroll
      for (int i = 0; i < 8; ++i) {
        int f = i * 256 + tid;
        *((u64*)(&hbuf[1][f >> 7][0]) + (f & 127)) = v[i];
      }
    }
    __syncthreads();  // barrier B: h1 staging visible

    if (L1h) {
#pragma unroll
      for (int kt = 0; kt < 8; ++kt) {
        half8 hC = *(const half8*)(&hbuf[1][bb][kt * 32 + q * 8]);
        half8 hD = *(const half8*)(&hbuf[1][bb][(kt + 8) * 32 + q * 8]);
        a1c = MFMA16(fW1h[kt], hC, a1c);
        a1d = MFMA16(fW1h[kt + 8], hD, a1d);
      }
    }

    if (L1) {
      f32x4 g1 = (a1 + a1b) + (a1c + a1d);
      float gi = sigf(g1.x), gf = sigf(g1.y), gg = tanhf_(g1.z), go = sigf(g1.w);
      c1 = gf * c1 + gi * gg;
      float h1v = go * tanhf_(c1);
      if (r == T) {
        // fc head (out zeroed by prep_kernel each call)
        float s0 = h1v * fcw0, s1 = h1v * fcw1;
        s0 += __shfl_xor(s0, 16); s0 += __shfl_xor(s0, 32);
        s1 += __shfl_xor(s1, 16); s1 += __shfl_xor(s1, 32);
        if (q == 0) {
          atomicAdd(out + (size_t)(c * 16 + bb) * 2 + 0, s0);
          atomicAdd(out + (size_t)(c * 16 + bb) * 2 + 1, s1);
        }
        if (wcl == 0 && lane < 32)
          atomicAdd(out + (size_t)(c * 16 + (lane & 15)) * 2 + (lane >> 4),
                    fcb[lane >> 4]);
      } else {
        size_t idx = (((size_t)(r & 1) * 8 + c) * 32 + 16 + bb) * 512 + ch;
        if (loc)
          exch[idx] = f2h(h1v);
        else
          __hip_atomic_store(exch + idx, f2h(h1v), __ATOMIC_RELAXED,
                             __HIP_MEMORY_SCOPE_AGENT);
        asm volatile("s_waitcnt vmcnt(0)" ::: "memory");  // h1 store complete
        if (lane == 0) {
          if (loc)
            __hip_atomic_store(flag1 + wcl, (unsigned)(r + 1), __ATOMIC_RELAXED,
                               __HIP_MEMORY_SCOPE_WORKGROUP);
          else
            __hip_atomic_store(flag1 + wcl, (unsigned)(r + 1), __ATOMIC_RELAXED,
                               __HIP_MEMORY_SCOPE_AGENT);
        }
      }
    }
  }
}

extern "C" void kernel_launch(void* const* d_in, const int* in_sizes, int n_in,
                              void* d_out, int out_size, void* d_ws,
                              size_t ws_size, hipStream_t stream) {
  const float* x = (const float*)d_in[0];
  const float* Wih0 = (const float*)d_in[1];
  const float* Whh0 = (const float*)d_in[2];
  const float* bih0 = (const float*)d_in[3];
  const float* bhh0 = (const float*)d_in[4];
  const float* Wih1 = (const float*)d_in[5];
  const float* Whh1 = (const float*)d_in[6];
  const float* bih1 = (const float*)d_in[7];
  const float* bhh1 = (const float*)d_in[8];
  const float* fcW = (const float*)d_in[9];
  const float* fcb = (const float*)d_in[10];

  char* ws = (char*)d_ws;  // uses < 4MB total
  unsigned* sync = (unsigned*)ws;
  unsigned short* exch = (unsigned short*)(ws + WS_EXCH_OFF);
  _Float16* xTw = (_Float16*)(ws + WS_XTW_OFF);
  float* out = (float*)d_out;

  prep_kernel<<<dim3(128), dim3(256), 0, stream>>>(x, xTw, sync, out);
  lstm_scan<<<dim3(256), dim3(256), 0, stream>>>(Whh0, bih0, bhh0, Wih1, Whh1,
                                                 bih1, bhh1, fcW, fcb, Wih0, x,
                                                 sync, exch, xTw, out);
}

// Round 6
// 4302.608 us; speedup vs baseline: 2.3032x; 1.1397x over previous
//
#include <hip/hip_runtime.h>
#include <hip/hip_fp16.h>

// ============================================================================
// LSTM_78176994722094: 2-layer LSTM (B=128, D_IN=128, T=1024, H=512) + fc head.
//
// R13: R7 skeleton + fragment-order exchange/LDS layout (kills ALL bank
// conflicts) + single rendezvous/barrier per round with per-wave flags.
//
// Forensic ledger:
//  R7  (4.1ms): LDS staging, 2 barriers/round, per-WG flag after end barrier.
//      512cy/round bank conflicts; flag lags the WG's slowest wave.
//  R8/R9 (7.9ms): hand-rolled sc-bit loads probe-FLUSH dirty L2 lines
//      (WRITE_SIZE 245MB). Only compiler __hip_atomic_load(AGENT) is safe.
//  R10 (9.9ms): direct per-wave fragment loads = 4x L2 volume. LDS staging
//      is REQUIRED dedup.
//  R12 (4.9ms): split per-layer flags FAILED: period = per-wave A+B work
//      regardless (same wave serializes both phases between its flags); the
//      split only doubled rendezvous jitter and re-read hbuf[0] (+50%
//      conflicts, 2.01e8). Register-reuse of h0 fragments is mandatory.
//
// R13 changes vs R7:
//  1. Exchange h layout -> MFMA fragment order [kt16][q4][bb16][8ch] per
//     (parity, cluster, layer). LDS hbuf mirrors it exactly. Staging is a
//     linear u64 identity copy (coalesced, bank-perfect); every ds_read_b128
//     hits 64 consecutive 16B chunks (0 conflicts by construction).
//  2. ONE spin + ONE barrier per round. Per-WAVE flags (128/cluster) set
//     after the wave's OWN vmcnt(0) (no end barrier, no WG-max lag). Safety:
//     flag(r) => wave's round-r LDS reads retired (data dependence through
//     the published h values); spin(r+1) waits all 128 flags => staging
//     never overwrites a buffer still being read. x-refresh stores also
//     drain before the flag (same vmcnt(0)).
//  3. Main loop reads each h0 fragment ONCE and feeds Whh0(hi/lo) AND
//     Wih1(hi/lo) chains from registers (R7 style).
//
// Workspace (<4MB):
//   [0, 16KB)          sync: claim@1024, mode@1040, arrive@1056,
//                      flags: word 1280 + c*128 + wcl (8 clusters x 128)
//   [64KB, 576KB)      h exchange: [parity2][cluster8][layer2][frag 16KB]
//   [640KB, 640KB+3MB) xTw: [slot3][cluster8][tau32][b16][d128] fp16
// ============================================================================

typedef _Float16 half8 __attribute__((ext_vector_type(8)));
typedef float f32x4 __attribute__((ext_vector_type(4)));
typedef unsigned long long u64;
typedef u64 u64x2 __attribute__((ext_vector_type(2)));

#define MFMA16(a, b, c) __builtin_amdgcn_mfma_f32_16x16x32_f16((a), (b), (c), 0, 0, 0)

#define WS_EXCH_OFF (64 << 10)
#define WS_XTW_OFF (640 << 10)
// sync word indices (u32) within ws base (prep zeroes words [0,4096))
#define SYNC_CLAIM 1024   // 8 u32
#define SYNC_MODE 1040    // 1 u32 (0=undecided, 1=fallback, 2=local)
#define SYNC_ARRIVE 1056  // 1 u32
#define SYNC_FLAG 1280    // 8 clusters x 128 u32 (per-wave, end-of-round)

__device__ __forceinline__ float sigf(float x) {
  return __builtin_amdgcn_rcpf(1.f + exp2f(-1.44269504f * x));
}
__device__ __forceinline__ float tanhf_(float x) {
  return 1.f - 2.f * __builtin_amdgcn_rcpf(1.f + exp2f(2.88539008f * x));
}
__device__ __forceinline__ unsigned short f2h(float x) {
  _Float16 h = (_Float16)x;  // RNE
  unsigned short b;
  __builtin_memcpy(&b, &h, 2);
  return b;
}
__device__ __forceinline__ u64 lda(const u64* p) {
  return __hip_atomic_load(p, __ATOMIC_RELAXED, __HIP_MEMORY_SCOPE_AGENT);
}

// split 8 fp32 weights -> hi fp16 + lo fp16 (lo = (w - hi) * 2^11)
__device__ __forceinline__ void cvt_split(const f32x4& a, const f32x4& b,
                                          half8& hi, half8& lo) {
#pragma unroll
  for (int i = 0; i < 4; ++i) {
    float w0 = a[i], w1 = b[i];
    _Float16 h0 = (_Float16)w0, h1 = (_Float16)w1;
    hi[i] = h0;
    hi[i + 4] = h1;
    lo[i] = (_Float16)((w0 - (float)h0) * 2048.0f);
    lo[i + 4] = (_Float16)((w1 - (float)h1) * 2048.0f);
  }
}
// scale a fragment by 2^-11 (exact exponent shift; v_pk_mul_f16)
__device__ __forceinline__ half8 hscale(half8 v) {
  half8 r;
#pragma unroll
  for (int i = 0; i < 8; ++i) r[i] = v[i] * (_Float16)4.8828125e-4f;
  return r;
}

// ---------------------------------------------------------------------------
// Prepass: fill xTw window 0 (t=0..31) slot 0, zero sync area (16KB) and out.
// ---------------------------------------------------------------------------
__global__ void __launch_bounds__(256) prep_kernel(const float* __restrict__ x,
                                                   _Float16* __restrict__ xTw,
                                                   unsigned* __restrict__ sync,
                                                   float* __restrict__ out) {
  const int bid = blockIdx.x;  // 128 = 8c * 16b
  const int c = bid >> 4, b16 = bid & 15;
  const int tid = threadIdx.x;
  if (bid == 0) {
#pragma unroll
    for (int i = 0; i < 16; ++i) sync[i * 256 + tid] = 0;  // 16KB sync area
    out[tid] = 0.f;  // out_size = B*OUT = 256
  }
  const int d = tid & 127, th = tid >> 7;  // th: tau half (0/1)
  const float* src = x + ((size_t)(c * 16 + b16) * 128 + d) * 1024 + th * 16;
  _Float16* dst = xTw + ((size_t)c * 32 + th * 16) * (16 * 128) + b16 * 128 + d;
#pragma unroll
  for (int i = 0; i < 16; ++i) dst[(size_t)i * (16 * 128)] = (_Float16)src[i];
}

// ---------------------------------------------------------------------------
// Persistent scan kernel. MFMA 16x16x32 f16 layouts (verified R1-R12):
//   A[m=lane&15][k=(lane>>4)*8+j], B[k=(lane>>4)*8+j][n=lane&15],
//   D[m=(lane>>4)*4+reg][n=lane&15].
// h exchange fragment order: half (kt,qq,bb,j) holds h[ch=kt*32+qq*8+j][bb].
// ---------------------------------------------------------------------------
__global__ void __launch_bounds__(256, 1) lstm_scan(
    const float* __restrict__ Whh0, const float* __restrict__ bih0,
    const float* __restrict__ bhh0, const float* __restrict__ Wih1,
    const float* __restrict__ Whh1, const float* __restrict__ bih1,
    const float* __restrict__ bhh1, const float* __restrict__ fcW,
    const float* __restrict__ fcb, const float* __restrict__ Wih0,
    const float* __restrict__ x, unsigned* __restrict__ sync,
    unsigned short* __restrict__ exch, _Float16* __restrict__ xTw,
    float* __restrict__ out) {
  // [layer][kt][q][bb][8] -- byte-identical to the exchange fragment block
  __shared__ __align__(16) _Float16 hbuf[2][16][4][16][8];  // 32KB
  __shared__ unsigned s_bcast[2];

  const int tid = threadIdx.x;
  const int wave = tid >> 6;
  const int lane = tid & 63;
  const int q = lane >> 4;
  const int bb = lane & 15;

  // ---- startup: XCD discovery + slot claim + grid barrier + mode decide ----
  unsigned xcc;
  asm("s_getreg_b32 %0, hwreg(HW_REG_XCC_ID)" : "=s"(xcc));
  xcc &= 7;
  unsigned* claim = sync + SYNC_CLAIM;
  unsigned* modew = sync + SYNC_MODE;
  unsigned* arrive = sync + SYNC_ARRIVE;
  if (tid == 0) {
    unsigned idx = __hip_atomic_fetch_add(claim + xcc, 1u, __ATOMIC_RELAXED,
                                          __HIP_MEMORY_SCOPE_AGENT);
    // (idx>>31)==0; data-dependency forces the claim RMW to complete first
    unsigned ord = __hip_atomic_fetch_add(arrive, 1u + (idx >> 31),
                                          __ATOMIC_RELAXED,
                                          __HIP_MEMORY_SCOPE_AGENT);
    if (ord == 255u) {  // last arriver decides for everyone
      unsigned ok = 1;
#pragma unroll
      for (int i = 0; i < 8; ++i)
        ok &= (__hip_atomic_load(claim + i, __ATOMIC_RELAXED,
                                 __HIP_MEMORY_SCOPE_AGENT) == 32u);
      __hip_atomic_store(modew, ok ? 2u : 1u, __ATOMIC_RELAXED,
                         __HIP_MEMORY_SCOPE_AGENT);
    }
    unsigned mv = 0;
    int guard = 0;
    for (;;) {
      mv = __hip_atomic_load(modew, __ATOMIC_RELAXED, __HIP_MEMORY_SCOPE_AGENT);
      if (mv != 0u) break;
      if (++guard > (1 << 18)) { mv = 1u; break; }
    }
    s_bcast[0] = mv;
    s_bcast[1] = idx;
  }
  __syncthreads();
  const bool loc = (s_bcast[0] == 2u);
  const int c = loc ? (int)xcc : (blockIdx.x >> 5);
  const int wg = loc ? (int)s_bcast[1] : (blockIdx.x & 31);

  const int wcl = wg * 4 + wave;  // wave id in cluster: 0..127
  const int chbase = wcl * 4;     // this wave's 4 hidden channels
  const int m = lane & 15;        // A-fragment row id for this lane
  const int arow = (m & 3) * 512 + chbase + (m >> 2);  // i,f,g,o gate order
  unsigned short* xtw16 = (unsigned short*)xTw;
  const u64* exch64c = (const u64*)exch;
  u64* hbuf64 = (u64*)hbuf;

  // ---- one-time: weight A-fragments (hi for all; lo for Whh0/Wih1/Wih0) ----
  half8 fW0[16], fW0lo[16], fW1i[16], fW1ilo[16], fW1h[16], fX[4], fXlo[4];
  {
    const float* p0 = Whh0 + (size_t)arow * 512 + q * 8;
    const float* p1 = Wih1 + (size_t)arow * 512 + q * 8;
    const float* p2 = Whh1 + (size_t)arow * 512 + q * 8;
#pragma unroll
    for (int kt = 0; kt < 16; ++kt) {
      f32x4 a0 = *(const f32x4*)(p0 + kt * 32), b0 = *(const f32x4*)(p0 + kt * 32 + 4);
      cvt_split(a0, b0, fW0[kt], fW0lo[kt]);
      f32x4 a1 = *(const f32x4*)(p1 + kt * 32), b1 = *(const f32x4*)(p1 + kt * 32 + 4);
      cvt_split(a1, b1, fW1i[kt], fW1ilo[kt]);
      f32x4 a2 = *(const f32x4*)(p2 + kt * 32), b2 = *(const f32x4*)(p2 + kt * 32 + 4);
      half8 dummy;
      cvt_split(a2, b2, fW1h[kt], dummy);  // hi only
    }
    const float* p3 = Wih0 + (size_t)arow * 128 + q * 8;
#pragma unroll
    for (int kt = 0; kt < 4; ++kt) {
      f32x4 a3 = *(const f32x4*)(p3 + kt * 32), b3 = *(const f32x4*)(p3 + kt * 32 + 4);
      cvt_split(a3, b3, fX[kt], fXlo[kt]);
    }
  }

  float b0v[4], b1v[4];
#pragma unroll
  for (int g = 0; g < 4; ++g) {
    int rrow = g * 512 + chbase + q;
    b0v[g] = bih0[rrow] + bhh0[rrow];
    b1v[g] = bih1[rrow] + bhh1[rrow];
  }
  const int ch = chbase + q;
  const float fcw0 = fcW[ch], fcw1 = fcW[512 + ch];
  // h publish position (fragment order): ushort offset within a layer block
  const int hoff = (((ch >> 5) * 4 + ((ch >> 3) & 3)) * 16) * 8 + (ch & 7) +
                   bb * 8;  // + bb*8: batch slot

  unsigned* flag = sync + SYNC_FLAG + c * 128;
  const u64* spinp = (const u64*)flag + lane;  // lane polls 2 wave-flags

  float c0 = 0.f, c1 = 0.f;
  const int T = 1024;
  for (int r = 0; r <= T; ++r) {
    const bool L0 = (r < T);
    const bool L1 = (r > 0);
    const bool L1h = (r > 1);
    const bool doref = (wave == 2 && r < 992 && (r & 3) == 0);
    const int p = (r - 1) & 1;

    // ---- x refresh LOAD only (stores deferred past the publishes). float4
    //      read keeps HBM line amplification at 4x. ----
    f32x4 xv4;
    int sw = 0, rw = 0, xb = 0, xd = 0;
    if (doref) {
      const int wnext = (r >> 5) + 1;
      sw = wnext % 3; rw = r & 31;
      xb = wg >> 1; xd = (wg & 1) * 64 + lane;
      xv4 = *(const f32x4*)(x + ((size_t)(c * 16 + xb) * 128 + xd) * 1024 +
                            wnext * 32 + rw);
    }

    // ---- x fragments for t=r, issued BEFORE the spin (slot written >=32
    //      rounds ago -> long drained to the local L2) ----
    half8 xf[4];
    if (L0) {
      const int s = (r >> 5) % 3, tau = r & 31;
      const u64* xp =
          (const u64*)xtw16 + (((size_t)(s * 8 + c) * 32 + tau) * 16 + bb) * 32;
#pragma unroll
      for (int kt = 0; kt < 4; ++kt) {
        u64x2 t2;
        t2.x = lda(xp + kt * 8 + q * 2);
        t2.y = lda(xp + kt * 8 + q * 2 + 1);
        xf[kt] = __builtin_bit_cast(half8, t2);
      }
    }

    // ---- ONE rendezvous: all 128 wave-flags >= r (covers h0[r-1], h1[r-2]).
    //      Then stage BOTH layers (32KB, linear identity copy). ----
    if (L1) {
      int guard = 0;
      for (;;) {
        u64 f = lda(spinp);
        bool ok = ((unsigned)f >= (unsigned)r) &&
                  ((unsigned)(f >> 32) >= (unsigned)r);
        if (__ballot(ok) == ~0ull) break;
        if (++guard > 8192) break;  // diagnostic fail-fast, never hangs
      }
      asm volatile("" ::: "memory");  // keep staging loads below the spin
      const u64* src = exch64c + ((size_t)p * 8 + c) * 4096 + tid;
      u64 v[16];
#pragma unroll
      for (int i = 0; i < 16; ++i) v[i] = lda(src + i * 256);
#pragma unroll
      for (int i = 0; i < 16; ++i) hbuf64[i * 256 + tid] = v[i];
    }
    __syncthreads();  // the ONLY barrier: staging visible to all waves

    // ---- L0 chains + L1-input chains share the h0 fragments (reg reuse) ----
    f32x4 a1 = {b1v[0], b1v[1], b1v[2], b1v[3]};
    f32x4 a1b = {0.f, 0.f, 0.f, 0.f};
    f32x4 a1c = a1b, a1d = a1b;
    if (L0) {
      f32x4 accX = {b0v[0], b0v[1], b0v[2], b0v[3]};
#pragma unroll
      for (int kt = 0; kt < 4; ++kt) {
        accX = MFMA16(fX[kt], xf[kt], accX);
        accX = MFMA16(fXlo[kt], hscale(xf[kt]), accX);
      }
      f32x4 a0 = {0.f, 0.f, 0.f, 0.f};
      f32x4 a0b = a0, a0l = a0, a0bl = a0;
      if (L1) {
#pragma unroll
        for (int kt = 0; kt < 8; ++kt) {
          half8 hA = *(const half8*)(&hbuf[0][kt][q][bb][0]);
          half8 hB = *(const half8*)(&hbuf[0][kt + 8][q][bb][0]);
          half8 hAs = hscale(hA), hBs = hscale(hB);
          a0 = MFMA16(fW0[kt], hA, a0);
          a0b = MFMA16(fW0[kt + 8], hB, a0b);
          a0l = MFMA16(fW0lo[kt], hAs, a0l);
          a0bl = MFMA16(fW0lo[kt + 8], hBs, a0bl);
          a1 = MFMA16(fW1i[kt], hA, a1);
          a1b = MFMA16(fW1i[kt + 8], hB, a1b);
          a1 = MFMA16(fW1ilo[kt], hAs, a1);
          a1b = MFMA16(fW1ilo[kt + 8], hBs, a1b);
        }
      }
      f32x4 g0 = accX + ((a0 + a0b) + (a0l + a0bl));
      float gi = sigf(g0.x), gf = sigf(g0.y), gg = tanhf_(g0.z), go = sigf(g0.w);
      c0 = gf * c0 + gi * gg;
      float h0v = go * tanhf_(c0);
      size_t idx = (((size_t)(r & 1) * 8 + c) * 16384) + hoff;  // layer 0
      if (loc)
        exch[idx] = f2h(h0v);  // plain -> dirty line in local L2
      else
        __hip_atomic_store(exch + idx, f2h(h0v), __ATOMIC_RELAXED,
                           __HIP_MEMORY_SCOPE_AGENT);
      // store drains while the L1 chains below run; one vmcnt(0) at round end
    } else if (L1) {
      // r == T: only the L1-input chain (no L0 work)
#pragma unroll
      for (int kt = 0; kt < 8; ++kt) {
        half8 hA = *(const half8*)(&hbuf[0][kt][q][bb][0]);
        half8 hB = *(const half8*)(&hbuf[0][kt + 8][q][bb][0]);
        half8 hAs = hscale(hA), hBs = hscale(hB);
        a1 = MFMA16(fW1i[kt], hA, a1);
        a1b = MFMA16(fW1i[kt + 8], hB, a1b);
        a1 = MFMA16(fW1ilo[kt], hAs, a1);
        a1b = MFMA16(fW1ilo[kt + 8], hBs, a1b);
      }
    }

    // ---- x refresh stores (overlap with L1h chain; drained by vmcnt(0)) ----
    if (doref) {
#pragma unroll
      for (int j = 0; j < 4; ++j) {
        size_t xidx =
            (((size_t)(sw * 8 + c) * 32 + rw + j) * 16 + xb) * 128 + xd;
        if (loc)
          xtw16[xidx] = f2h(xv4[j]);
        else
          __hip_atomic_store(xtw16 + xidx, f2h(xv4[j]), __ATOMIC_RELAXED,
                             __HIP_MEMORY_SCOPE_AGENT);
      }
    }

    // ---- L1 recurrent chain (Whh1 * h1[r-2]) ----
    if (L1h) {
#pragma unroll
      for (int kt = 0; kt < 8; ++kt) {
        half8 hC = *(const half8*)(&hbuf[1][kt][q][bb][0]);
        half8 hD = *(const half8*)(&hbuf[1][kt + 8][q][bb][0]);
        a1c = MFMA16(fW1h[kt], hC, a1c);
        a1d = MFMA16(fW1h[kt + 8], hD, a1d);
      }
    }

    if (L1) {
      f32x4 g1 = (a1 + a1b) + (a1c + a1d);
      float gi = sigf(g1.x), gf = sigf(g1.y), gg = tanhf_(g1.z), go = sigf(g1.w);
      c1 = gf * c1 + gi * gg;
      float h1v = go * tanhf_(c1);
      if (r == T) {
        // fc head (out zeroed by prep_kernel each call)
        float s0 = h1v * fcw0, s1 = h1v * fcw1;
        s0 += __shfl_xor(s0, 16); s0 += __shfl_xor(s0, 32);
        s1 += __shfl_xor(s1, 16); s1 += __shfl_xor(s1, 32);
        if (q == 0) {
          atomicAdd(out + (size_t)(c * 16 + bb) * 2 + 0, s0);
          atomicAdd(out + (size_t)(c * 16 + bb) * 2 + 1, s1);
        }
        if (wcl == 0 && lane < 32)
          atomicAdd(out + (size_t)(c * 16 + (lane & 15)) * 2 + (lane >> 4),
                    fcb[lane >> 4]);
      } else {
        size_t idx = (((size_t)(r & 1) * 8 + c) * 16384) + 8192 + hoff;  // L1
        if (loc)
          exch[idx] = f2h(h1v);
        else
          __hip_atomic_store(exch + idx, f2h(h1v), __ATOMIC_RELAXED,
                             __HIP_MEMORY_SCOPE_AGENT);
      }
    }

    // ---- per-wave end-of-round publish: own drain, own flag ----
    if (r < T) {
      asm volatile("s_waitcnt vmcnt(0)" ::: "memory");  // h0+h1+x drained
      if (lane == 0) {
        if (loc)
          __hip_atomic_store(flag + wcl, (unsigned)(r + 1), __ATOMIC_RELAXED,
                             __HIP_MEMORY_SCOPE_WORKGROUP);
        else
          __hip_atomic_store(flag + wcl, (unsigned)(r + 1), __ATOMIC_RELAXED,
                             __HIP_MEMORY_SCOPE_AGENT);
      }
    }
  }
}

extern "C" void kernel_launch(void* const* d_in, const int* in_sizes, int n_in,
                              void* d_out, int out_size, void* d_ws,
                              size_t ws_size, hipStream_t stream) {
  const float* x = (const float*)d_in[0];
  const float* Wih0 = (const float*)d_in[1];
  const float* Whh0 = (const float*)d_in[2];
  const float* bih0 = (const float*)d_in[3];
  const float* bhh0 = (const float*)d_in[4];
  const float* Wih1 = (const float*)d_in[5];
  const float* Whh1 = (const float*)d_in[6];
  const float* bih1 = (const float*)d_in[7];
  const float* bhh1 = (const float*)d_in[8];
  const float* fcW = (const float*)d_in[9];
  const float* fcb = (const float*)d_in[10];

  char* ws = (char*)d_ws;  // uses < 4MB total
  unsigned* sync = (unsigned*)ws;
  unsigned short* exch = (unsigned short*)(ws + WS_EXCH_OFF);
  _Float16* xTw = (_Float16*)(ws + WS_XTW_OFF);
  float* out = (float*)d_out;

  prep_kernel<<<dim3(128), dim3(256), 0, stream>>>(x, xTw, sync, out);
  lstm_scan<<<dim3(256), dim3(256), 0, stream>>>(Whh0, bih0, bhh0, Wih1, Whh1,
                                                 bih1, bhh1, fcW, fcb, Wih0, x,
                                                 sync, exch, xTw, out);
}

// Round 8
// 3641.216 us; speedup vs baseline: 2.7215x; 1.1816x over previous
//
#include <hip/hip_runtime.h>
#include <hip/hip_fp16.h>

// ============================================================================
// LSTM_78176994722094: 2-layer LSTM (B=128, D_IN=128, T=1024, H=512) + fc head.
//
// R15 = R13 with loc-mode staging/xf loads switched from __hip_atomic_load
// to PLAIN vector loads (u64x2 -> registers -> ds_write_b128). No
// global_load_lds (R14's untested DMA path is the prime suspect for the R7
// container failure: an undrained vmcnt would hang the wave -> timeout ->
// container kill). Plain loads are compiler-tracked and fully pipelined --
// which is exactly what the R14 hypothesis needs tested:
//
// HYPOTHESIS (fits every measured round): __hip_atomic_load does NOT
// pipeline; each staging load is a serial ~270cy L2 round-trip:
//   R7/R13: 24 atomic loads*270 ~ 6.5K + 3K work ~ 10K cy/round ✓ (meas. 10K)
//   R10:    72 loads -> ~23K ✓   R12: 24 loads + 2x rendezvous ~ 11.5K ✓
//
// Stale-L1 safety for plain loads (loc mode only): the 32KB staging read
// itself thrashes the 32KB L1 every round, so same-parity exchange lines
// (last touched 2 rounds = 64KB of fills ago) are always evicted; xTw lines
// are 96 rounds cold. absmax is the canary (expect 1.22e-4). Fallback mode
// keeps the atomic path (cross-XCD L2 staleness is real there).
//
// Forensic ledger:
//  R7  (4.1ms): LDS staging, 2 barriers, per-WG end flag.
//  R8/R9 (7.9ms): hand sc-bit loads flush dirty L2 (WRITE_SIZE 245MB).
//  R10 (9.9ms): per-wave direct fragment loads: 4x L2 volume + serial loads.
//  R12 (4.9ms): split flags = period unchanged; double rendezvous. Register
//      reuse of h0 fragments is mandatory.
//  R13 (4.3ms): fragment-order exchange; conflicts 2e8->0; 1 barrier;
//      per-wave flags. Time unchanged => mechanics-bound, not work-bound.
//  R14 (no data): container failed twice; global_load_lds suspect.
//
// Workspace (<4MB):
//   [0, 16KB)          sync: claim@1024, mode@1040, arrive@1056,
//                      flags: word 1280 + c*128 + wcl (8 clusters x 128)
//   [64KB, 576KB)      h exchange: [parity2][cluster8][layer2][frag 16KB]
//   [640KB, 640KB+3MB) xTw: [slot3][cluster8][tau32][b16][d128] fp16
// ============================================================================

typedef _Float16 half8 __attribute__((ext_vector_type(8)));
typedef float f32x4 __attribute__((ext_vector_type(4)));
typedef unsigned long long u64;
typedef u64 u64x2 __attribute__((ext_vector_type(2)));

#define MFMA16(a, b, c) __builtin_amdgcn_mfma_f32_16x16x32_f16((a), (b), (c), 0, 0, 0)

#define WS_EXCH_OFF (64 << 10)
#define WS_XTW_OFF (640 << 10)
// sync word indices (u32) within ws base (prep zeroes words [0,4096))
#define SYNC_CLAIM 1024   // 8 u32
#define SYNC_MODE 1040    // 1 u32 (0=undecided, 1=fallback, 2=local)
#define SYNC_ARRIVE 1056  // 1 u32
#define SYNC_FLAG 1280    // 8 clusters x 128 u32 (per-wave, end-of-round)

__device__ __forceinline__ float sigf(float x) {
  return __builtin_amdgcn_rcpf(1.f + exp2f(-1.44269504f * x));
}
__device__ __forceinline__ float tanhf_(float x) {
  return 1.f - 2.f * __builtin_amdgcn_rcpf(1.f + exp2f(2.88539008f * x));
}
__device__ __forceinline__ unsigned short f2h(float x) {
  _Float16 h = (_Float16)x;  // RNE
  unsigned short b;
  __builtin_memcpy(&b, &h, 2);
  return b;
}
__device__ __forceinline__ u64 lda(const u64* p) {
  return __hip_atomic_load(p, __ATOMIC_RELAXED, __HIP_MEMORY_SCOPE_AGENT);
}

// split 8 fp32 weights -> hi fp16 + lo fp16 (lo = (w - hi) * 2^11)
__device__ __forceinline__ void cvt_split(const f32x4& a, const f32x4& b,
                                          half8& hi, half8& lo) {
#pragma unroll
  for (int i = 0; i < 4; ++i) {
    float w0 = a[i], w1 = b[i];
    _Float16 h0 = (_Float16)w0, h1 = (_Float16)w1;
    hi[i] = h0;
    hi[i + 4] = h1;
    lo[i] = (_Float16)((w0 - (float)h0) * 2048.0f);
    lo[i + 4] = (_Float16)((w1 - (float)h1) * 2048.0f);
  }
}
// scale a fragment by 2^-11 (exact exponent shift; v_pk_mul_f16)
__device__ __forceinline__ half8 hscale(half8 v) {
  half8 r;
#pragma unroll
  for (int i = 0; i < 8; ++i) r[i] = v[i] * (_Float16)4.8828125e-4f;
  return r;
}

// ---------------------------------------------------------------------------
// Prepass: fill xTw window 0 (t=0..31) slot 0, zero sync area (16KB) and out.
// ---------------------------------------------------------------------------
__global__ void __launch_bounds__(256) prep_kernel(const float* __restrict__ x,
                                                   _Float16* __restrict__ xTw,
                                                   unsigned* __restrict__ sync,
                                                   float* __restrict__ out) {
  const int bid = blockIdx.x;  // 128 = 8c * 16b
  const int c = bid >> 4, b16 = bid & 15;
  const int tid = threadIdx.x;
  if (bid == 0) {
#pragma unroll
    for (int i = 0; i < 16; ++i) sync[i * 256 + tid] = 0;  // 16KB sync area
    out[tid] = 0.f;  // out_size = B*OUT = 256
  }
  const int d = tid & 127, th = tid >> 7;  // th: tau half (0/1)
  const float* src = x + ((size_t)(c * 16 + b16) * 128 + d) * 1024 + th * 16;
  _Float16* dst = xTw + ((size_t)c * 32 + th * 16) * (16 * 128) + b16 * 128 + d;
#pragma unroll
  for (int i = 0; i < 16; ++i) dst[(size_t)i * (16 * 128)] = (_Float16)src[i];
}

// ---------------------------------------------------------------------------
// Persistent scan kernel. MFMA 16x16x32 f16 layouts (verified R1-R13):
//   A[m=lane&15][k=(lane>>4)*8+j], B[k=(lane>>4)*8+j][n=lane&15],
//   D[m=(lane>>4)*4+reg][n=lane&15].
// h exchange fragment order: half (kt,qq,bb,j) holds h[ch=kt*32+qq*8+j][bb].
// ---------------------------------------------------------------------------
__global__ void __launch_bounds__(256, 1) lstm_scan(
    const float* __restrict__ Whh0, const float* __restrict__ bih0,
    const float* __restrict__ bhh0, const float* __restrict__ Wih1,
    const float* __restrict__ Whh1, const float* __restrict__ bih1,
    const float* __restrict__ bhh1, const float* __restrict__ fcW,
    const float* __restrict__ fcb, const float* __restrict__ Wih0,
    const float* __restrict__ x, unsigned* __restrict__ sync,
    unsigned short* __restrict__ exch, _Float16* __restrict__ xTw,
    float* __restrict__ out) {
  // [layer][kt][q][bb][8] -- byte-identical to the exchange fragment block
  __shared__ __align__(16) _Float16 hbuf[2][16][4][16][8];  // 32KB
  __shared__ unsigned s_bcast[2];

  const int tid = threadIdx.x;
  const int wave = tid >> 6;
  const int lane = tid & 63;
  const int q = lane >> 4;
  const int bb = lane & 15;

  // ---- startup: XCD discovery + slot claim + grid barrier + mode decide ----
  unsigned xcc;
  asm("s_getreg_b32 %0, hwreg(HW_REG_XCC_ID)" : "=s"(xcc));
  xcc &= 7;
  unsigned* claim = sync + SYNC_CLAIM;
  unsigned* modew = sync + SYNC_MODE;
  unsigned* arrive = sync + SYNC_ARRIVE;
  if (tid == 0) {
    unsigned idx = __hip_atomic_fetch_add(claim + xcc, 1u, __ATOMIC_RELAXED,
                                          __HIP_MEMORY_SCOPE_AGENT);
    // (idx>>31)==0; data-dependency forces the claim RMW to complete first
    unsigned ord = __hip_atomic_fetch_add(arrive, 1u + (idx >> 31),
                                          __ATOMIC_RELAXED,
                                          __HIP_MEMORY_SCOPE_AGENT);
    if (ord == 255u) {  // last arriver decides for everyone
      unsigned ok = 1;
#pragma unroll
      for (int i = 0; i < 8; ++i)
        ok &= (__hip_atomic_load(claim + i, __ATOMIC_RELAXED,
                                 __HIP_MEMORY_SCOPE_AGENT) == 32u);
      __hip_atomic_store(modew, ok ? 2u : 1u, __ATOMIC_RELAXED,
                         __HIP_MEMORY_SCOPE_AGENT);
    }
    unsigned mv = 0;
    int guard = 0;
    for (;;) {
      mv = __hip_atomic_load(modew, __ATOMIC_RELAXED, __HIP_MEMORY_SCOPE_AGENT);
      if (mv != 0u) break;
      if (++guard > (1 << 18)) { mv = 1u; break; }
    }
    s_bcast[0] = mv;
    s_bcast[1] = idx;
  }
  __syncthreads();
  const bool loc = (s_bcast[0] == 2u);
  const int c = loc ? (int)xcc : (blockIdx.x >> 5);
  const int wg = loc ? (int)s_bcast[1] : (blockIdx.x & 31);

  const int wcl = wg * 4 + wave;  // wave id in cluster: 0..127
  const int chbase = wcl * 4;     // this wave's 4 hidden channels
  const int m = lane & 15;        // A-fragment row id for this lane
  const int arow = (m & 3) * 512 + chbase + (m >> 2);  // i,f,g,o gate order
  unsigned short* xtw16 = (unsigned short*)xTw;
  const u64* exch64c = (const u64*)exch;
  u64* hbuf64 = (u64*)hbuf;

  // ---- one-time: weight A-fragments (hi for all; lo for Whh0/Wih1/Wih0) ----
  half8 fW0[16], fW0lo[16], fW1i[16], fW1ilo[16], fW1h[16], fX[4], fXlo[4];
  {
    const float* p0 = Whh0 + (size_t)arow * 512 + q * 8;
    const float* p1 = Wih1 + (size_t)arow * 512 + q * 8;
    const float* p2 = Whh1 + (size_t)arow * 512 + q * 8;
#pragma unroll
    for (int kt = 0; kt < 16; ++kt) {
      f32x4 a0 = *(const f32x4*)(p0 + kt * 32), b0 = *(const f32x4*)(p0 + kt * 32 + 4);
      cvt_split(a0, b0, fW0[kt], fW0lo[kt]);
      f32x4 a1 = *(const f32x4*)(p1 + kt * 32), b1 = *(const f32x4*)(p1 + kt * 32 + 4);
      cvt_split(a1, b1, fW1i[kt], fW1ilo[kt]);
      f32x4 a2 = *(const f32x4*)(p2 + kt * 32), b2 = *(const f32x4*)(p2 + kt * 32 + 4);
      half8 dummy;
      cvt_split(a2, b2, fW1h[kt], dummy);  // hi only
    }
    const float* p3 = Wih0 + (size_t)arow * 128 + q * 8;
#pragma unroll
    for (int kt = 0; kt < 4; ++kt) {
      f32x4 a3 = *(const f32x4*)(p3 + kt * 32), b3 = *(const f32x4*)(p3 + kt * 32 + 4);
      cvt_split(a3, b3, fX[kt], fXlo[kt]);
    }
  }

  float b0v[4], b1v[4];
#pragma unroll
  for (int g = 0; g < 4; ++g) {
    int rrow = g * 512 + chbase + q;
    b0v[g] = bih0[rrow] + bhh0[rrow];
    b1v[g] = bih1[rrow] + bhh1[rrow];
  }
  const int ch = chbase + q;
  const float fcw0 = fcW[ch], fcw1 = fcW[512 + ch];
  // h publish position (fragment order): ushort offset within a layer block
  const int hoff = (((ch >> 5) * 4 + ((ch >> 3) & 3)) * 16) * 8 + (ch & 7) +
                   bb * 8;  // + bb*8: batch slot

  unsigned* flag = sync + SYNC_FLAG + c * 128;
  const u64* spinp = (const u64*)flag + lane;  // lane polls 2 wave-flags

  float c0 = 0.f, c1 = 0.f;
  const int T = 1024;
  for (int r = 0; r <= T; ++r) {
    const bool L0 = (r < T);
    const bool L1 = (r > 0);
    const bool L1h = (r > 1);
    const bool doref = (wave == 2 && r < 992 && (r & 3) == 0);
    const int p = (r - 1) & 1;

    // ---- x refresh LOAD only (stores deferred past the publishes). float4
    //      read keeps HBM line amplification at 4x. ----
    f32x4 xv4;
    int sw = 0, rw = 0, xb = 0, xd = 0;
    if (doref) {
      const int wnext = (r >> 5) + 1;
      sw = wnext % 3; rw = r & 31;
      xb = wg >> 1; xd = (wg & 1) * 64 + lane;
      xv4 = *(const f32x4*)(x + ((size_t)(c * 16 + xb) * 128 + xd) * 1024 +
                            wnext * 32 + rw);
    }

    // ---- x fragments for t=r, issued BEFORE the spin (slot written >=32
    //      rounds ago; xTw lines last READ 96 rounds ago -> L1-evicted).
    //      loc: plain pipelined 16B loads. fallback: atomic (cross-XCD). ----
    half8 xf[4];
    if (L0) {
      const int s = (r >> 5) % 3, tau = r & 31;
      const u64* xp =
          (const u64*)xtw16 + (((size_t)(s * 8 + c) * 32 + tau) * 16 + bb) * 32;
      if (loc) {
#pragma unroll
        for (int kt = 0; kt < 4; ++kt)
          xf[kt] = __builtin_bit_cast(half8, *(const u64x2*)(xp + kt * 8 + q * 2));
      } else {
#pragma unroll
        for (int kt = 0; kt < 4; ++kt) {
          u64x2 t2;
          t2.x = lda(xp + kt * 8 + q * 2);
          t2.y = lda(xp + kt * 8 + q * 2 + 1);
          xf[kt] = __builtin_bit_cast(half8, t2);
        }
      }
    }

    // ---- ONE rendezvous: all 128 wave-flags >= r (covers h0[r-1], h1[r-2]).
    //      Then stage BOTH layers (32KB, linear identity copy).
    //      loc: 8 PLAIN u64x2 loads/thread (pipelined, 8 outstanding) +
    //      8 ds_write_b128. fallback: R13 atomic path. ----
    if (L1) {
      int guard = 0;
      for (;;) {
        u64 f = lda(spinp);
        bool ok = ((unsigned)f >= (unsigned)r) &&
                  ((unsigned)(f >> 32) >= (unsigned)r);
        if (__ballot(ok) == ~0ull) break;
        if (++guard > 8192) break;  // diagnostic fail-fast, never hangs
      }
      asm volatile("" ::: "memory");  // keep staging below the spin
      if (loc) {
        const u64x2* src =
            (const u64x2*)(exch64c + ((size_t)p * 8 + c) * 4096) + tid;
        u64x2 v[8];
#pragma unroll
        for (int i = 0; i < 8; ++i) v[i] = src[i * 256];
        u64x2* dst = (u64x2*)hbuf64 + tid;
#pragma unroll
        for (int i = 0; i < 8; ++i) dst[i * 256] = v[i];
      } else {
        const u64* src = exch64c + ((size_t)p * 8 + c) * 4096 + tid;
        u64 v[16];
#pragma unroll
        for (int i = 0; i < 16; ++i) v[i] = lda(src + i * 256);
#pragma unroll
        for (int i = 0; i < 16; ++i) hbuf64[i * 256 + tid] = v[i];
      }
    }
    __syncthreads();  // the ONLY barrier: staging visible to all waves

    // ---- L0 chains + L1-input chains share the h0 fragments (reg reuse) ----
    f32x4 a1 = {b1v[0], b1v[1], b1v[2], b1v[3]};
    f32x4 a1b = {0.f, 0.f, 0.f, 0.f};
    f32x4 a1c = a1b, a1d = a1b;
    if (L0) {
      f32x4 accX = {b0v[0], b0v[1], b0v[2], b0v[3]};
#pragma unroll
      for (int kt = 0; kt < 4; ++kt) {
        accX = MFMA16(fX[kt], xf[kt], accX);
        accX = MFMA16(fXlo[kt], hscale(xf[kt]), accX);
      }
      f32x4 a0 = {0.f, 0.f, 0.f, 0.f};
      f32x4 a0b = a0, a0l = a0, a0bl = a0;
      if (L1) {
#pragma unroll
        for (int kt = 0; kt < 8; ++kt) {
          half8 hA = *(const half8*)(&hbuf[0][kt][q][bb][0]);
          half8 hB = *(const half8*)(&hbuf[0][kt + 8][q][bb][0]);
          half8 hAs = hscale(hA), hBs = hscale(hB);
          a0 = MFMA16(fW0[kt], hA, a0);
          a0b = MFMA16(fW0[kt + 8], hB, a0b);
          a0l = MFMA16(fW0lo[kt], hAs, a0l);
          a0bl = MFMA16(fW0lo[kt + 8], hBs, a0bl);
          a1 = MFMA16(fW1i[kt], hA, a1);
          a1b = MFMA16(fW1i[kt + 8], hB, a1b);
          a1 = MFMA16(fW1ilo[kt], hAs, a1);
          a1b = MFMA16(fW1ilo[kt + 8], hBs, a1b);
        }
      }
      f32x4 g0 = accX + ((a0 + a0b) + (a0l + a0bl));
      float gi = sigf(g0.x), gf = sigf(g0.y), gg = tanhf_(g0.z), go = sigf(g0.w);
      c0 = gf * c0 + gi * gg;
      float h0v = go * tanhf_(c0);
      size_t idx = (((size_t)(r & 1) * 8 + c) * 16384) + hoff;  // layer 0
      if (loc)
        exch[idx] = f2h(h0v);  // plain -> dirty line in local L2
      else
        __hip_atomic_store(exch + idx, f2h(h0v), __ATOMIC_RELAXED,
                           __HIP_MEMORY_SCOPE_AGENT);
      // store drains while the L1 chains below run; one vmcnt(0) at round end
    } else if (L1) {
      // r == T: only the L1-input chain (no L0 work)
#pragma unroll
      for (int kt = 0; kt < 8; ++kt) {
        half8 hA = *(const half8*)(&hbuf[0][kt][q][bb][0]);
        half8 hB = *(const half8*)(&hbuf[0][kt + 8][q][bb][0]);
        half8 hAs = hscale(hA), hBs = hscale(hB);
        a1 = MFMA16(fW1i[kt], hA, a1);
        a1b = MFMA16(fW1i[kt + 8], hB, a1b);
        a1 = MFMA16(fW1ilo[kt], hAs, a1);
        a1b = MFMA16(fW1ilo[kt + 8], hBs, a1b);
      }
    }

    // ---- x refresh stores (overlap with L1h chain; drained by vmcnt(0)) ----
    if (doref) {
#pragma unroll
      for (int j = 0; j < 4; ++j) {
        size_t xidx =
            (((size_t)(sw * 8 + c) * 32 + rw + j) * 16 + xb) * 128 + xd;
        if (loc)
          xtw16[xidx] = f2h(xv4[j]);
        else
          __hip_atomic_store(xtw16 + xidx, f2h(xv4[j]), __ATOMIC_RELAXED,
                             __HIP_MEMORY_SCOPE_AGENT);
      }
    }

    // ---- L1 recurrent chain (Whh1 * h1[r-2]) ----
    if (L1h) {
#pragma unroll
      for (int kt = 0; kt < 8; ++kt) {
        half8 hC = *(const half8*)(&hbuf[1][kt][q][bb][0]);
        half8 hD = *(const half8*)(&hbuf[1][kt + 8][q][bb][0]);
        a1c = MFMA16(fW1h[kt], hC, a1c);
        a1d = MFMA16(fW1h[kt + 8], hD, a1d);
      }
    }

    if (L1) {
      f32x4 g1 = (a1 + a1b) + (a1c + a1d);
      float gi = sigf(g1.x), gf = sigf(g1.y), gg = tanhf_(g1.z), go = sigf(g1.w);
      c1 = gf * c1 + gi * gg;
      float h1v = go * tanhf_(c1);
      if (r == T) {
        // fc head (out zeroed by prep_kernel each call)
        float s0 = h1v * fcw0, s1 = h1v * fcw1;
        s0 += __shfl_xor(s0, 16); s0 += __shfl_xor(s0, 32);
        s1 += __shfl_xor(s1, 16); s1 += __shfl_xor(s1, 32);
        if (q == 0) {
          atomicAdd(out + (size_t)(c * 16 + bb) * 2 + 0, s0);
          atomicAdd(out + (size_t)(c * 16 + bb) * 2 + 1, s1);
        }
        if (wcl == 0 && lane < 32)
          atomicAdd(out + (size_t)(c * 16 + (lane & 15)) * 2 + (lane >> 4),
                    fcb[lane >> 4]);
      } else {
        size_t idx = (((size_t)(r & 1) * 8 + c) * 16384) + 8192 + hoff;  // L1
        if (loc)
          exch[idx] = f2h(h1v);
        else
          __hip_atomic_store(exch + idx, f2h(h1v), __ATOMIC_RELAXED,
                             __HIP_MEMORY_SCOPE_AGENT);
      }
    }

    // ---- per-wave end-of-round publish: own drain, own flag ----
    if (r < T) {
      asm volatile("s_waitcnt vmcnt(0)" ::: "memory");  // h0+h1+x drained
      if (lane == 0) {
        if (loc)
          __hip_atomic_store(flag + wcl, (unsigned)(r + 1), __ATOMIC_RELAXED,
                             __HIP_MEMORY_SCOPE_WORKGROUP);
        else
          __hip_atomic_store(flag + wcl, (unsigned)(r + 1), __ATOMIC_RELAXED,
                             __HIP_MEMORY_SCOPE_AGENT);
      }
    }
  }
}

extern "C" void kernel_launch(void* const* d_in, const int* in_sizes, int n_in,
                              void* d_out, int out_size, void* d_ws,
                              size_t ws_size, hipStream_t stream) {
  const float* x = (const float*)d_in[0];
  const float* Wih0 = (const float*)d_in[1];
  const float* Whh0 = (const float*)d_in[2];
  const float* bih0 = (const float*)d_in[3];
  const float* bhh0 = (const float*)d_in[4];
  const float* Wih1 = (const float*)d_in[5];
  const float* Whh1 = (const float*)d_in[6];
  const float* bih1 = (const float*)d_in[7];
  const float* bhh1 = (const float*)d_in[8];
  const float* fcW = (const float*)d_in[9];
  const float* fcb = (const float*)d_in[10];

  char* ws = (char*)d_ws;  // uses < 4MB total
  unsigned* sync = (unsigned*)ws;
  unsigned short* exch = (unsigned short*)(ws + WS_EXCH_OFF);
  _Float16* xTw = (_Float16*)(ws + WS_XTW_OFF);
  float* out = (float*)d_out;

  prep_kernel<<<dim3(128), dim3(256), 0, stream>>>(x, xTw, sync, out);
  lstm_scan<<<dim3(256), dim3(256), 0, stream>>>(Whh0, bih0, bhh0, Wih1, Whh1,
                                                 bih1, bhh1, fcW, fcb, Wih0, x,
                                                 sync, exch, xTw, out);
}

// Round 9
// 3039.818 us; speedup vs baseline: 3.2599x; 1.1978x over previous
//
#include <hip/hip_runtime.h>
#include <hip/hip_fp16.h>

// ============================================================================
// LSTM_78176994722094: 2-layer LSTM (B=128, D_IN=128, T=1024, H=512) + fc head.
//
// R16: wave-specialized two-stage pipeline. 512 blocks x 256 thr, 2 blocks/CU
// (__launch_bounds__(256,2)). Per cluster: 32 L0-blocks own ONLY the h0
// recurrence; 32 L1-blocks run layer 1 skewed behind, throttling L0 via a
// 4-slot h0 buffer (L0 may run 3 rounds ahead). The h0 period no longer
// contains ANY layer-1 work, staging drops 32->16KB, MFMA 88->40 on the
// critical stage.
//
// WHY (R15 forensics): round = 8.7Kcy but modeled serial work ~4K. The period
// is one wave's FULL serial chain (spin->stage32KB->barrier->72 MFMA->epi->
// 16 MFMA->epi->drain->flag) because one wave executes both layers between
// its own flag stores (R12 lesson: flag placement can't fix this; only
// removing L1 work from the critical wave can).
//
// Forensic ledger:
//  R7  (4.1ms): monolithic round, 2 barriers, per-WG flag.
//  R8/R9 (7.9ms): hand sc-bit loads flush dirty L2 (WRITE_SIZE 245MB).
//  R10 (9.9ms): no LDS dedup -> 4x L2 volume. Staging is required.
//  R12 (4.9ms): split flags, same wave does both layers -> period unchanged.
//  R13 (4.3ms): fragment-order exchange: conflicts 2e8->0. Time unchanged.
//  R15 (3.64ms): plain loads for staging/xf (atomics cost ~65cy extra each;
//      absmax 1.22e-4 held -> loc-mode L1 staleness disproven by thrash).
//
// Workspace (<4MB):
//   [0, 16KB)        sync: claim@1024 (8), mode@1040, arrive@1056,
//                    flag0: word 1280 + c*128 + wcl (L0 team, 8x128)
//                    flag1: word 2304 + c*128 + wcl (L1 team, 8x128)
//   [64KB, 576KB)    h0 exchange: [slot4][cluster8][frag 16KB]
//   [576KB, 832KB)   h1 exchange: [parity2][cluster8][frag 16KB]
//   [832KB, 3904KB)  xTw: [slot3][cluster8][tau32][b16][d128] fp16
// ============================================================================

typedef _Float16 half8 __attribute__((ext_vector_type(8)));
typedef float f32x4 __attribute__((ext_vector_type(4)));
typedef unsigned long long u64;
typedef u64 u64x2 __attribute__((ext_vector_type(2)));

#define MFMA16(a, b, c) __builtin_amdgcn_mfma_f32_16x16x32_f16((a), (b), (c), 0, 0, 0)

#define WS_H0_OFF (64 << 10)
#define WS_H1_OFF (576 << 10)
#define WS_XTW_OFF (832 << 10)
#define SYNC_CLAIM 1024   // 8 u32 (count to 64 each)
#define SYNC_MODE 1040    // 1 u32 (0=undecided, 1=fallback, 2=local)
#define SYNC_ARRIVE 1056  // 1 u32 (count to 512)
#define SYNC_FLAG0 1280   // 8 clusters x 128 u32 (L0 team)
#define SYNC_FLAG1 2304   // 8 clusters x 128 u32 (L1 team)

__device__ __forceinline__ float sigf(float x) {
  return __builtin_amdgcn_rcpf(1.f + exp2f(-1.44269504f * x));
}
__device__ __forceinline__ float tanhf_(float x) {
  return 1.f - 2.f * __builtin_amdgcn_rcpf(1.f + exp2f(2.88539008f * x));
}
__device__ __forceinline__ unsigned short f2h(float x) {
  _Float16 h = (_Float16)x;  // RNE
  unsigned short b;
  __builtin_memcpy(&b, &h, 2);
  return b;
}
__device__ __forceinline__ u64 lda(const u64* p) {
  return __hip_atomic_load(p, __ATOMIC_RELAXED, __HIP_MEMORY_SCOPE_AGENT);
}

// split 8 fp32 weights -> hi fp16 + lo fp16 (lo = (w - hi) * 2^11)
__device__ __forceinline__ void cvt_split(const f32x4& a, const f32x4& b,
                                          half8& hi, half8& lo) {
#pragma unroll
  for (int i = 0; i < 4; ++i) {
    float w0 = a[i], w1 = b[i];
    _Float16 h0 = (_Float16)w0, h1 = (_Float16)w1;
    hi[i] = h0;
    hi[i + 4] = h1;
    lo[i] = (_Float16)((w0 - (float)h0) * 2048.0f);
    lo[i + 4] = (_Float16)((w1 - (float)h1) * 2048.0f);
  }
}
// scale a fragment by 2^-11 (exact exponent shift; v_pk_mul_f16)
__device__ __forceinline__ half8 hscale(half8 v) {
  half8 r;
#pragma unroll
  for (int i = 0; i < 8; ++i) r[i] = v[i] * (_Float16)4.8828125e-4f;
  return r;
}

// ---------------------------------------------------------------------------
// Prepass: fill xTw window 0 (t=0..31) slot 0, zero sync area (16KB) and out.
// ---------------------------------------------------------------------------
__global__ void __launch_bounds__(256) prep_kernel(const float* __restrict__ x,
                                                   _Float16* __restrict__ xTw,
                                                   unsigned* __restrict__ sync,
                                                   float* __restrict__ out) {
  const int bid = blockIdx.x;  // 128 = 8c * 16b
  const int c = bid >> 4, b16 = bid & 15;
  const int tid = threadIdx.x;
  if (bid == 0) {
#pragma unroll
    for (int i = 0; i < 16; ++i) sync[i * 256 + tid] = 0;  // 16KB sync area
    out[tid] = 0.f;  // out_size = B*OUT = 256
  }
  const int d = tid & 127, th = tid >> 7;  // th: tau half (0/1)
  const float* src = x + ((size_t)(c * 16 + b16) * 128 + d) * 1024 + th * 16;
  _Float16* dst = xTw + ((size_t)c * 32 + th * 16) * (16 * 128) + b16 * 128 + d;
#pragma unroll
  for (int i = 0; i < 16; ++i) dst[(size_t)i * (16 * 128)] = (_Float16)src[i];
}

// ---------------------------------------------------------------------------
// Persistent scan kernel, role-split. MFMA 16x16x32 f16 layouts (verified
// R1-R15): A[m=lane&15][k=(lane>>4)*8+j], B[k][n=lane&15],
// D[m=(lane>>4)*4+reg][n]. h exchange in MFMA fragment order:
// half (kt,qq,bb,j) holds h[ch=kt*32+qq*8+j][bb].
// ---------------------------------------------------------------------------
__global__ void __launch_bounds__(256, 2) lstm_scan(
    const float* __restrict__ Whh0, const float* __restrict__ bih0,
    const float* __restrict__ bhh0, const float* __restrict__ Wih1,
    const float* __restrict__ Whh1, const float* __restrict__ bih1,
    const float* __restrict__ bhh1, const float* __restrict__ fcW,
    const float* __restrict__ fcb, const float* __restrict__ Wih0,
    const float* __restrict__ x, unsigned* __restrict__ sync,
    unsigned short* __restrict__ exch, _Float16* __restrict__ xTw,
    float* __restrict__ out) {
  // L0 blocks use hbuf[0] only (16KB); L1 blocks use both halves (32KB).
  __shared__ __align__(16) _Float16 hbuf[2][16][4][16][8];
  __shared__ unsigned s_bcast[2];

  const int tid = threadIdx.x;
  const int wave = tid >> 6;
  const int lane = tid & 63;
  const int q = lane >> 4;
  const int bb = lane & 15;

  // ---- startup: XCD discovery + slot claim + grid barrier + mode decide ----
  unsigned xcc;
  asm("s_getreg_b32 %0, hwreg(HW_REG_XCC_ID)" : "=s"(xcc));
  xcc &= 7;
  unsigned* claim = sync + SYNC_CLAIM;
  unsigned* modew = sync + SYNC_MODE;
  unsigned* arrive = sync + SYNC_ARRIVE;
  if (tid == 0) {
    unsigned idx = __hip_atomic_fetch_add(claim + xcc, 1u, __ATOMIC_RELAXED,
                                          __HIP_MEMORY_SCOPE_AGENT);
    // (idx>>31)==0; data-dependency forces the claim RMW to complete first
    unsigned ord = __hip_atomic_fetch_add(arrive, 1u + (idx >> 31),
                                          __ATOMIC_RELAXED,
                                          __HIP_MEMORY_SCOPE_AGENT);
    if (ord == 511u) {  // last arriver decides for everyone
      unsigned ok = 1;
#pragma unroll
      for (int i = 0; i < 8; ++i)
        ok &= (__hip_atomic_load(claim + i, __ATOMIC_RELAXED,
                                 __HIP_MEMORY_SCOPE_AGENT) == 64u);
      __hip_atomic_store(modew, ok ? 2u : 1u, __ATOMIC_RELAXED,
                         __HIP_MEMORY_SCOPE_AGENT);
    }
    unsigned mv = 0;
    int guard = 0;
    for (;;) {
      mv = __hip_atomic_load(modew, __ATOMIC_RELAXED, __HIP_MEMORY_SCOPE_AGENT);
      if (mv != 0u) break;
      if (++guard > (1 << 18)) { mv = 1u; break; }
    }
    s_bcast[0] = mv;
    s_bcast[1] = idx;
  }
  __syncthreads();
  const bool loc = (s_bcast[0] == 2u);
  const unsigned idx = s_bcast[1];
  bool roleL1;
  int c, wg;
  if (loc) {
    c = (int)xcc;
    roleL1 = idx >= 32u;
    wg = roleL1 ? (int)idx - 32 : (int)idx;
  } else {
    const int b = blockIdx.x;
    roleL1 = b >= 256;
    const int b2 = roleL1 ? b - 256 : b;
    c = b2 >> 5;
    wg = b2 & 31;
  }

  const int wcl = wg * 4 + wave;  // wave id in team: 0..127
  const int chbase = wcl * 4;     // this wave's 4 hidden channels
  const int m = lane & 15;        // A-fragment row id for this lane
  const int arow = (m & 3) * 512 + chbase + (m >> 2);  // i,f,g,o gate order
  unsigned short* xtw16 = (unsigned short*)xTw;
  unsigned short* exch1 = exch + ((512 << 10) >> 1);  // h1 base (ushort)
  const int ch = chbase + q;
  // h publish position (fragment order): ushort offset within a layer block
  const int hoff = (((ch >> 5) * 4 + ((ch >> 3) & 3)) * 16) * 8 + (ch & 7) +
                   bb * 8;

  unsigned* flag0 = sync + SYNC_FLAG0 + c * 128;
  unsigned* flag1 = sync + SYNC_FLAG1 + c * 128;
  const u64* s0p = (const u64*)flag0 + lane;  // lane polls 2 wave-flags
  const u64* s1p = (const u64*)flag1 + lane;
  const int T = 1024;

  if (!roleL1) {
    // ======================= L0 team: h0 recurrence =======================
    half8 fW0[16], fW0lo[16], fX[4], fXlo[4];
    {
      const float* p0 = Whh0 + (size_t)arow * 512 + q * 8;
#pragma unroll
      for (int kt = 0; kt < 16; ++kt) {
        f32x4 a0 = *(const f32x4*)(p0 + kt * 32),
              b0 = *(const f32x4*)(p0 + kt * 32 + 4);
        cvt_split(a0, b0, fW0[kt], fW0lo[kt]);
      }
      const float* p3 = Wih0 + (size_t)arow * 128 + q * 8;
#pragma unroll
      for (int kt = 0; kt < 4; ++kt) {
        f32x4 a3 = *(const f32x4*)(p3 + kt * 32),
              b3 = *(const f32x4*)(p3 + kt * 32 + 4);
        cvt_split(a3, b3, fX[kt], fXlo[kt]);
      }
    }
    float b0v[4];
#pragma unroll
    for (int g = 0; g < 4; ++g) {
      int rrow = g * 512 + chbase + q;
      b0v[g] = bih0[rrow] + bhh0[rrow];
    }

    float c0 = 0.f;
    for (int r = 0; r < T; ++r) {
      const bool doref = (wave == 2 && r < 992 && (r & 3) == 0);

      // x refresh LOAD only (stores after epilogue; HBM latency hidden
      // under spin+stage+compute)
      f32x4 xv4;
      int sw = 0, rw = 0, xb = 0, xd = 0;
      if (doref) {
        const int wnext = (r >> 5) + 1;
        sw = wnext % 3; rw = r & 31;
        xb = wg >> 1; xd = (wg & 1) * 64 + lane;
        xv4 = *(const f32x4*)(x + ((size_t)(c * 16 + xb) * 128 + xd) * 1024 +
                              wnext * 32 + rw);
      }

      // x fragments for t=r (slot written >=32 rounds ago; L1-thrashed)
      half8 xf[4];
      {
        const int s = (r >> 5) % 3, tau = r & 31;
        const u64* xp = (const u64*)xtw16 +
                        (((size_t)(s * 8 + c) * 32 + tau) * 16 + bb) * 32;
        if (loc) {
#pragma unroll
          for (int kt = 0; kt < 4; ++kt)
            xf[kt] =
                __builtin_bit_cast(half8, *(const u64x2*)(xp + kt * 8 + q * 2));
        } else {
#pragma unroll
          for (int kt = 0; kt < 4; ++kt) {
            u64x2 t2;
            t2.x = lda(xp + kt * 8 + q * 2);
            t2.y = lda(xp + kt * 8 + q * 2 + 1);
            xf[kt] = __builtin_bit_cast(half8, t2);
          }
        }
      }

      if (r > 0) {
        // spin: own team's h0[r-1] ready AND L1 done with h0[r-4]
        // (writing slot r&3; flag1 >= r-3 <=> L1 round r-4 complete)
        int guard = 0;
        for (;;) {
          u64 f0 = lda(s0p), f1 = lda(s1p);
          bool ok = ((int)(unsigned)f0 >= r) && ((int)(f0 >> 32) >= r) &&
                    ((int)(unsigned)f1 >= r - 3) && ((int)(f1 >> 32) >= r - 3);
          if (__ballot(ok) == ~0ull) break;
          if (++guard > 4096) break;  // diagnostic fail-fast, never hangs
        }
        asm volatile("" ::: "memory");  // keep staging below the spin
        // stage h0[r-1] (16KB) from slot (r-1)&3
        if (loc) {
          const u64x2* src =
              (const u64x2*)exch + ((size_t)((r - 1) & 3) * 8 + c) * 1024 + tid;
          u64x2 v[4];
#pragma unroll
          for (int i = 0; i < 4; ++i) v[i] = src[i * 256];
          u64x2* dst = (u64x2*)hbuf + tid;
#pragma unroll
          for (int i = 0; i < 4; ++i) dst[i * 256] = v[i];
        } else {
          const u64* src =
              (const u64*)exch + ((size_t)((r - 1) & 3) * 8 + c) * 2048 + tid;
          u64 v[8];
#pragma unroll
          for (int i = 0; i < 8; ++i) v[i] = lda(src + i * 256);
          u64* dst = (u64*)hbuf + tid;
#pragma unroll
          for (int i = 0; i < 8; ++i) dst[i * 256] = v[i];
        }
      }
      __syncthreads();

      f32x4 accX = {b0v[0], b0v[1], b0v[2], b0v[3]};
#pragma unroll
      for (int kt = 0; kt < 4; ++kt) {
        accX = MFMA16(fX[kt], xf[kt], accX);
        accX = MFMA16(fXlo[kt], hscale(xf[kt]), accX);
      }
      f32x4 a0 = {0.f, 0.f, 0.f, 0.f};
      f32x4 a0b = a0, a0l = a0, a0bl = a0;
      if (r > 0) {
#pragma unroll
        for (int kt = 0; kt < 8; ++kt) {
          half8 hA = *(const half8*)(&hbuf[0][kt][q][bb][0]);
          half8 hB = *(const half8*)(&hbuf[0][kt + 8][q][bb][0]);
          a0 = MFMA16(fW0[kt], hA, a0);
          a0b = MFMA16(fW0[kt + 8], hB, a0b);
          a0l = MFMA16(fW0lo[kt], hscale(hA), a0l);
          a0bl = MFMA16(fW0lo[kt + 8], hscale(hB), a0bl);
        }
      }
      f32x4 g0 = accX + ((a0 + a0b) + (a0l + a0bl));
      float gi = sigf(g0.x), gf = sigf(g0.y), gg = tanhf_(g0.z),
            go = sigf(g0.w);
      c0 = gf * c0 + gi * gg;
      float h0v = go * tanhf_(c0);
      size_t hidx = ((size_t)(r & 3) * 8 + c) * 8192 + hoff;
      if (loc)
        exch[hidx] = f2h(h0v);  // plain -> dirty line in local L2
      else
        __hip_atomic_store(exch + hidx, f2h(h0v), __ATOMIC_RELAXED,
                           __HIP_MEMORY_SCOPE_AGENT);

      if (doref) {
#pragma unroll
        for (int j = 0; j < 4; ++j) {
          size_t xidx =
              (((size_t)(sw * 8 + c) * 32 + rw + j) * 16 + xb) * 128 + xd;
          if (loc)
            xtw16[xidx] = f2h(xv4[j]);
          else
            __hip_atomic_store(xtw16 + xidx, f2h(xv4[j]), __ATOMIC_RELAXED,
                               __HIP_MEMORY_SCOPE_AGENT);
        }
      }

      asm volatile("s_waitcnt vmcnt(0)" ::: "memory");  // h0 + x drained
      if (lane == 0) {
        if (loc)
          __hip_atomic_store(flag0 + wcl, (unsigned)(r + 1), __ATOMIC_RELAXED,
                             __HIP_MEMORY_SCOPE_WORKGROUP);
        else
          __hip_atomic_store(flag0 + wcl, (unsigned)(r + 1), __ATOMIC_RELAXED,
                             __HIP_MEMORY_SCOPE_AGENT);
      }
    }
  } else {
    // ================== L1 team: layer 1, skewed behind ==================
    half8 fW1i[16], fW1ilo[16], fW1h[16];
    {
      const float* p1 = Wih1 + (size_t)arow * 512 + q * 8;
      const float* p2 = Whh1 + (size_t)arow * 512 + q * 8;
#pragma unroll
      for (int kt = 0; kt < 16; ++kt) {
        f32x4 a1 = *(const f32x4*)(p1 + kt * 32),
              b1 = *(const f32x4*)(p1 + kt * 32 + 4);
        cvt_split(a1, b1, fW1i[kt], fW1ilo[kt]);
        f32x4 a2 = *(const f32x4*)(p2 + kt * 32),
              b2 = *(const f32x4*)(p2 + kt * 32 + 4);
        half8 dummy;
        cvt_split(a2, b2, fW1h[kt], dummy);  // hi only
      }
    }
    float b1v[4];
#pragma unroll
    for (int g = 0; g < 4; ++g) {
      int rrow = g * 512 + chbase + q;
      b1v[g] = bih1[rrow] + bhh1[rrow];
    }
    const float fcw0 = fcW[ch], fcw1 = fcW[512 + ch];

    float c1 = 0.f;
    for (int t = 0; t < T; ++t) {
      // spin: h0[t] published (flag0 >= t+1) and own team's h1[t-1] ready
      // (flag1 >= t; also protects the h1 parity slot we write below)
      {
        int guard = 0;
        for (;;) {
          u64 f0 = lda(s0p), f1 = lda(s1p);
          bool ok = ((int)(unsigned)f0 >= t + 1) && ((int)(f0 >> 32) >= t + 1) &&
                    ((int)(unsigned)f1 >= t) && ((int)(f1 >> 32) >= t);
          if (__ballot(ok) == ~0ull) break;
          if (++guard > 4096) break;  // diagnostic fail-fast, never hangs
        }
        asm volatile("" ::: "memory");  // keep staging below the spin
      }
      // stage h0[t] (16KB, slot t&3) into hbuf[0]; h1[t-1] into hbuf[1]
      if (loc) {
        const u64x2* src0 =
            (const u64x2*)exch + ((size_t)(t & 3) * 8 + c) * 1024 + tid;
        u64x2 v0[4];
#pragma unroll
        for (int i = 0; i < 4; ++i) v0[i] = src0[i * 256];
        u64x2* dst0 = (u64x2*)hbuf + tid;
#pragma unroll
        for (int i = 0; i < 4; ++i) dst0[i * 256] = v0[i];
        if (t > 0) {
          const u64x2* src1 = (const u64x2*)exch1 +
                              ((size_t)((t - 1) & 1) * 8 + c) * 1024 + tid;
          u64x2 v1[4];
#pragma unroll
          for (int i = 0; i < 4; ++i) v1[i] = src1[i * 256];
          u64x2* dst1 = (u64x2*)hbuf + 1024 + tid;
#pragma unroll
          for (int i = 0; i < 4; ++i) dst1[i * 256] = v1[i];
        }
      } else {
        const u64* src0 =
            (const u64*)exch + ((size_t)(t & 3) * 8 + c) * 2048 + tid;
        u64 v0[8];
#pragma unroll
        for (int i = 0; i < 8; ++i) v0[i] = lda(src0 + i * 256);
        u64* dst0 = (u64*)hbuf + tid;
#pragma unroll
        for (int i = 0; i < 8; ++i) dst0[i * 256] = v0[i];
        if (t > 0) {
          const u64* src1 =
              (const u64*)exch1 + ((size_t)((t - 1) & 1) * 8 + c) * 2048 + tid;
          u64 v1[8];
#pragma unroll
          for (int i = 0; i < 8; ++i) v1[i] = lda(src1 + i * 256);
          u64* dst1 = (u64*)hbuf + 2048 + tid;
#pragma unroll
          for (int i = 0; i < 8; ++i) dst1[i * 256] = v1[i];
        }
      }
      __syncthreads();

      f32x4 a1 = {b1v[0], b1v[1], b1v[2], b1v[3]};
      f32x4 a1b = {0.f, 0.f, 0.f, 0.f};
      f32x4 a1c = a1b, a1d = a1b;
#pragma unroll
      for (int kt = 0; kt < 8; ++kt) {
        half8 hA = *(const half8*)(&hbuf[0][kt][q][bb][0]);
        half8 hB = *(const half8*)(&hbuf[0][kt + 8][q][bb][0]);
        a1 = MFMA16(fW1i[kt], hA, a1);
        a1b = MFMA16(fW1i[kt + 8], hB, a1b);
        a1 = MFMA16(fW1ilo[kt], hscale(hA), a1);
        a1b = MFMA16(fW1ilo[kt + 8], hscale(hB), a1b);
      }
      if (t > 0) {
#pragma unroll
        for (int kt = 0; kt < 8; ++kt) {
          half8 hC = *(const half8*)(&hbuf[1][kt][q][bb][0]);
          half8 hD = *(const half8*)(&hbuf[1][kt + 8][q][bb][0]);
          a1c = MFMA16(fW1h[kt], hC, a1c);
          a1d = MFMA16(fW1h[kt + 8], hD, a1d);
        }
      }
      f32x4 g1 = (a1 + a1b) + (a1c + a1d);
      float gi = sigf(g1.x), gf = sigf(g1.y), gg = tanhf_(g1.z),
            go = sigf(g1.w);
      c1 = gf * c1 + gi * gg;
      float h1v = go * tanhf_(c1);

      if (t == T - 1) {
        // fc head (out zeroed by prep_kernel each call)
        float s0 = h1v * fcw0, s1 = h1v * fcw1;
        s0 += __shfl_xor(s0, 16); s0 += __shfl_xor(s0, 32);
        s1 += __shfl_xor(s1, 16); s1 += __shfl_xor(s1, 32);
        if (q == 0) {
          atomicAdd(out + (size_t)(c * 16 + bb) * 2 + 0, s0);
          atomicAdd(out + (size_t)(c * 16 + bb) * 2 + 1, s1);
        }
        if (wcl == 0 && lane < 32)
          atomicAdd(out + (size_t)(c * 16 + (lane & 15)) * 2 + (lane >> 4),
                    fcb[lane >> 4]);
      } else {
        size_t hidx = ((size_t)(t & 1) * 8 + c) * 8192 + hoff;
        if (loc)
          exch1[hidx] = f2h(h1v);
        else
          __hip_atomic_store(exch1 + hidx, f2h(h1v), __ATOMIC_RELAXED,
                             __HIP_MEMORY_SCOPE_AGENT);
      }
      asm volatile("s_waitcnt vmcnt(0)" ::: "memory");  // h1 drained
      if (lane == 0) {
        if (loc)
          __hip_atomic_store(flag1 + wcl, (unsigned)(t + 1), __ATOMIC_RELAXED,
                             __HIP_MEMORY_SCOPE_WORKGROUP);
        else
          __hip_atomic_store(flag1 + wcl, (unsigned)(t + 1), __ATOMIC_RELAXED,
                             __HIP_MEMORY_SCOPE_AGENT);
      }
    }
  }
}

extern "C" void kernel_launch(void* const* d_in, const int* in_sizes, int n_in,
                              void* d_out, int out_size, void* d_ws,
                              size_t ws_size, hipStream_t stream) {
  const float* x = (const float*)d_in[0];
  const float* Wih0 = (const float*)d_in[1];
  const float* Whh0 = (const float*)d_in[2];
  const float* bih0 = (const float*)d_in[3];
  const float* bhh0 = (const float*)d_in[4];
  const float* Wih1 = (const float*)d_in[5];
  const float* Whh1 = (const float*)d_in[6];
  const float* bih1 = (const float*)d_in[7];
  const float* bhh1 = (const float*)d_in[8];
  const float* fcW = (const float*)d_in[9];
  const float* fcb = (const float*)d_in[10];

  char* ws = (char*)d_ws;  // uses < 4MB total
  unsigned* sync = (unsigned*)ws;
  unsigned short* exch = (unsigned short*)(ws + WS_H0_OFF);
  _Float16* xTw = (_Float16*)(ws + WS_XTW_OFF);
  float* out = (float*)d_out;

  prep_kernel<<<dim3(128), dim3(256), 0, stream>>>(x, xTw, sync, out);
  lstm_scan<<<dim3(512), dim3(256), 0, stream>>>(Whh0, bih0, bhh0, Wih1, Whh1,
                                                 bih1, bhh1, fcW, fcb, Wih0, x,
                                                 sync, exch, xTw, out);
}

// Round 10
// 2887.504 us; speedup vs baseline: 3.4319x; 1.0527x over previous
//
#include <hip/hip_runtime.h>
#include <hip/hip_fp16.h>

// ============================================================================
// LSTM_78176994722094: 2-layer LSTM (B=128, D_IN=128, T=1024, H=512) + fc head.
//
// R17 = R16 with the L1 team software-pipelined + two convoy fixes.
//
// R16 post-mortem: role split worked (3641->3039us, occupancy 12->22.6%).
// Steady-state period = max(T_L0, T_L1); T_L1 (32KB stage + 48 MFMA) is the
// heavier stage and throttles L0 through the flag1>=r-3 backpressure.
//
// R17 changes:
//  1. L1 pipelined: per round, ONLY the h1-recurrence segment (stage h1 16KB,
//     16 MFMA Whh1, epilogue, publish, flag1) sits between flag1 stores. The
//     32-MFMA Wih1*h0[t+1] chain runs AFTER the flag (h0[t+1] is available
//     early thanks to L0's 3-round lead; a1 partial held in registers).
//     -> T_L1_serial < T_L0 -> throttle vanishes, period -> T_L0.
//  2. doref convoy fix: xTw refresh stores moved AFTER the flag store (they
//     were inside wave2's vmcnt(0) drain -> every 4th round all 127 other
//     waves waited on wave2's delayed flag).
//  3. L0's accX chain (8 MFMA on xf only) moved before the spin.
//  Numerics byte-identical (same MFMA accumulation order). absmax 1.22e-4.
//
// Forensic ledger:
//  R7 4.1ms monolithic | R8/R9 7.9ms hand sc-bits flush L2 | R10 9.9ms no
//  dedup | R12 4.9ms split flags same-wave-both-layers | R13 4.3ms
//  fragment-order exchange (conflicts 2e8->0) | R15 3.64ms plain loads |
//  R16 3.04ms role split (L0 team | L1 team, 2 blocks/CU).
//
// Workspace (<4MB):
//   [0, 16KB)        sync: claim@1024 (8), mode@1040, arrive@1056,
//                    flag0: word 1280 + c*128 + wcl (L0 team, 8x128)
//                    flag1: word 2304 + c*128 + wcl (L1 team, 8x128)
//   [64KB, 576KB)    h0 exchange: [slot4][cluster8][frag 16KB]
//   [576KB, 832KB)   h1 exchange: [parity2][cluster8][frag 16KB]
//   [832KB, 3904KB)  xTw: [slot3][cluster8][tau32][b16][d128] fp16
// ============================================================================

typedef _Float16 half8 __attribute__((ext_vector_type(8)));
typedef float f32x4 __attribute__((ext_vector_type(4)));
typedef unsigned long long u64;
typedef u64 u64x2 __attribute__((ext_vector_type(2)));

#define MFMA16(a, b, c) __builtin_amdgcn_mfma_f32_16x16x32_f16((a), (b), (c), 0, 0, 0)

#define WS_H0_OFF (64 << 10)
#define WS_H1_OFF (576 << 10)
#define WS_XTW_OFF (832 << 10)
#define SYNC_CLAIM 1024   // 8 u32 (count to 64 each)
#define SYNC_MODE 1040    // 1 u32 (0=undecided, 1=fallback, 2=local)
#define SYNC_ARRIVE 1056  // 1 u32 (count to 512)
#define SYNC_FLAG0 1280   // 8 clusters x 128 u32 (L0 team)
#define SYNC_FLAG1 2304   // 8 clusters x 128 u32 (L1 team)

__device__ __forceinline__ float sigf(float x) {
  return __builtin_amdgcn_rcpf(1.f + exp2f(-1.44269504f * x));
}
__device__ __forceinline__ float tanhf_(float x) {
  return 1.f - 2.f * __builtin_amdgcn_rcpf(1.f + exp2f(2.88539008f * x));
}
__device__ __forceinline__ unsigned short f2h(float x) {
  _Float16 h = (_Float16)x;  // RNE
  unsigned short b;
  __builtin_memcpy(&b, &h, 2);
  return b;
}
__device__ __forceinline__ u64 lda(const u64* p) {
  return __hip_atomic_load(p, __ATOMIC_RELAXED, __HIP_MEMORY_SCOPE_AGENT);
}

// split 8 fp32 weights -> hi fp16 + lo fp16 (lo = (w - hi) * 2^11)
__device__ __forceinline__ void cvt_split(const f32x4& a, const f32x4& b,
                                          half8& hi, half8& lo) {
#pragma unroll
  for (int i = 0; i < 4; ++i) {
    float w0 = a[i], w1 = b[i];
    _Float16 h0 = (_Float16)w0, h1 = (_Float16)w1;
    hi[i] = h0;
    hi[i + 4] = h1;
    lo[i] = (_Float16)((w0 - (float)h0) * 2048.0f);
    lo[i + 4] = (_Float16)((w1 - (float)h1) * 2048.0f);
  }
}
// scale a fragment by 2^-11 (exact exponent shift; v_pk_mul_f16)
__device__ __forceinline__ half8 hscale(half8 v) {
  half8 r;
#pragma unroll
  for (int i = 0; i < 8; ++i) r[i] = v[i] * (_Float16)4.8828125e-4f;
  return r;
}

// ---------------------------------------------------------------------------
// Prepass: fill xTw window 0 (t=0..31) slot 0, zero sync area (16KB) and out.
// ---------------------------------------------------------------------------
__global__ void __launch_bounds__(256) prep_kernel(const float* __restrict__ x,
                                                   _Float16* __restrict__ xTw,
                                                   unsigned* __restrict__ sync,
                                                   float* __restrict__ out) {
  const int bid = blockIdx.x;  // 128 = 8c * 16b
  const int c = bid >> 4, b16 = bid & 15;
  const int tid = threadIdx.x;
  if (bid == 0) {
#pragma unroll
    for (int i = 0; i < 16; ++i) sync[i * 256 + tid] = 0;  // 16KB sync area
    out[tid] = 0.f;  // out_size = B*OUT = 256
  }
  const int d = tid & 127, th = tid >> 7;  // th: tau half (0/1)
  const float* src = x + ((size_t)(c * 16 + b16) * 128 + d) * 1024 + th * 16;
  _Float16* dst = xTw + ((size_t)c * 32 + th * 16) * (16 * 128) + b16 * 128 + d;
#pragma unroll
  for (int i = 0; i < 16; ++i) dst[(size_t)i * (16 * 128)] = (_Float16)src[i];
}

// ---------------------------------------------------------------------------
// Persistent scan kernel, role-split + L1 software pipeline. MFMA layouts
// (verified R1-R16): A[m=lane&15][k=(lane>>4)*8+j], B[k][n=lane&15],
// D[m=(lane>>4)*4+reg][n]. h exchange in MFMA fragment order:
// half (kt,qq,bb,j) holds h[ch=kt*32+qq*8+j][bb].
// ---------------------------------------------------------------------------
__global__ void __launch_bounds__(256, 2) lstm_scan(
    const float* __restrict__ Whh0, const float* __restrict__ bih0,
    const float* __restrict__ bhh0, const float* __restrict__ Wih1,
    const float* __restrict__ Whh1, const float* __restrict__ bih1,
    const float* __restrict__ bhh1, const float* __restrict__ fcW,
    const float* __restrict__ fcb, const float* __restrict__ Wih0,
    const float* __restrict__ x, unsigned* __restrict__ sync,
    unsigned short* __restrict__ exch, _Float16* __restrict__ xTw,
    float* __restrict__ out) {
  // hbuf[0]: L0's h0 stage / L1's h1 stage. hbuf[1],hbuf[2]: L1's h0 parity
  // double-buffer (tail-phase prefetch races the previous round's reads).
  __shared__ __align__(16) _Float16 hbuf[3][16][4][16][8];  // 48KB
  __shared__ unsigned s_bcast[2];

  const int tid = threadIdx.x;
  const int wave = tid >> 6;
  const int lane = tid & 63;
  const int q = lane >> 4;
  const int bb = lane & 15;

  // ---- startup: XCD discovery + slot claim + grid barrier + mode decide ----
  unsigned xcc;
  asm("s_getreg_b32 %0, hwreg(HW_REG_XCC_ID)" : "=s"(xcc));
  xcc &= 7;
  unsigned* claim = sync + SYNC_CLAIM;
  unsigned* modew = sync + SYNC_MODE;
  unsigned* arrive = sync + SYNC_ARRIVE;
  if (tid == 0) {
    unsigned idx = __hip_atomic_fetch_add(claim + xcc, 1u, __ATOMIC_RELAXED,
                                          __HIP_MEMORY_SCOPE_AGENT);
    // (idx>>31)==0; data-dependency forces the claim RMW to complete first
    unsigned ord = __hip_atomic_fetch_add(arrive, 1u + (idx >> 31),
                                          __ATOMIC_RELAXED,
                                          __HIP_MEMORY_SCOPE_AGENT);
    if (ord == 511u) {  // last arriver decides for everyone
      unsigned ok = 1;
#pragma unroll
      for (int i = 0; i < 8; ++i)
        ok &= (__hip_atomic_load(claim + i, __ATOMIC_RELAXED,
                                 __HIP_MEMORY_SCOPE_AGENT) == 64u);
      __hip_atomic_store(modew, ok ? 2u : 1u, __ATOMIC_RELAXED,
                         __HIP_MEMORY_SCOPE_AGENT);
    }
    unsigned mv = 0;
    int guard = 0;
    for (;;) {
      mv = __hip_atomic_load(modew, __ATOMIC_RELAXED, __HIP_MEMORY_SCOPE_AGENT);
      if (mv != 0u) break;
      if (++guard > (1 << 18)) { mv = 1u; break; }
    }
    s_bcast[0] = mv;
    s_bcast[1] = idx;
  }
  __syncthreads();
  const bool loc = (s_bcast[0] == 2u);
  const unsigned idx = s_bcast[1];
  bool roleL1;
  int c, wg;
  if (loc) {
    c = (int)xcc;
    roleL1 = idx >= 32u;
    wg = roleL1 ? (int)idx - 32 : (int)idx;
  } else {
    const int b = blockIdx.x;
    roleL1 = b >= 256;
    const int b2 = roleL1 ? b - 256 : b;
    c = b2 >> 5;
    wg = b2 & 31;
  }

  const int wcl = wg * 4 + wave;  // wave id in team: 0..127
  const int chbase = wcl * 4;     // this wave's 4 hidden channels
  const int m = lane & 15;        // A-fragment row id for this lane
  const int arow = (m & 3) * 512 + chbase + (m >> 2);  // i,f,g,o gate order
  unsigned short* xtw16 = (unsigned short*)xTw;
  unsigned short* exch1 = exch + ((512 << 10) >> 1);  // h1 base (ushort)
  const int ch = chbase + q;
  // h publish position (fragment order): ushort offset within a layer block
  const int hoff = (((ch >> 5) * 4 + ((ch >> 3) & 3)) * 16) * 8 + (ch & 7) +
                   bb * 8;

  unsigned* flag0 = sync + SYNC_FLAG0 + c * 128;
  unsigned* flag1 = sync + SYNC_FLAG1 + c * 128;
  const u64* s0p = (const u64*)flag0 + lane;  // lane polls 2 wave-flags
  const u64* s1p = (const u64*)flag1 + lane;
  const int T = 1024;

  if (!roleL1) {
    // ======================= L0 team: h0 recurrence =======================
    half8 fW0[16], fW0lo[16], fX[4], fXlo[4];
    {
      const float* p0 = Whh0 + (size_t)arow * 512 + q * 8;
#pragma unroll
      for (int kt = 0; kt < 16; ++kt) {
        f32x4 a0 = *(const f32x4*)(p0 + kt * 32),
              b0 = *(const f32x4*)(p0 + kt * 32 + 4);
        cvt_split(a0, b0, fW0[kt], fW0lo[kt]);
      }
      const float* p3 = Wih0 + (size_t)arow * 128 + q * 8;
#pragma unroll
      for (int kt = 0; kt < 4; ++kt) {
        f32x4 a3 = *(const f32x4*)(p3 + kt * 32),
              b3 = *(const f32x4*)(p3 + kt * 32 + 4);
        cvt_split(a3, b3, fX[kt], fXlo[kt]);
      }
    }
    float b0v[4];
#pragma unroll
    for (int g = 0; g < 4; ++g) {
      int rrow = g * 512 + chbase + q;
      b0v[g] = bih0[rrow] + bhh0[rrow];
    }

    float c0 = 0.f;
    for (int r = 0; r < T; ++r) {
      const bool doref = (wave == 2 && r < 992 && (r & 3) == 0);

      // x refresh LOAD only (stores after the flag; HBM latency hidden
      // under spin+stage+compute)
      f32x4 xv4;
      int sw = 0, rw = 0, xb = 0, xd = 0;
      if (doref) {
        const int wnext = (r >> 5) + 1;
        sw = wnext % 3; rw = r & 31;
        xb = wg >> 1; xd = (wg & 1) * 64 + lane;
        xv4 = *(const f32x4*)(x + ((size_t)(c * 16 + xb) * 128 + xd) * 1024 +
                              wnext * 32 + rw);
      }

      // x fragments for t=r (slot written >=32 rounds ago; L1-thrashed)
      half8 xf[4];
      {
        const int s = (r >> 5) % 3, tau = r & 31;
        const u64* xp = (const u64*)xtw16 +
                        (((size_t)(s * 8 + c) * 32 + tau) * 16 + bb) * 32;
        if (loc) {
#pragma unroll
          for (int kt = 0; kt < 4; ++kt)
            xf[kt] =
                __builtin_bit_cast(half8, *(const u64x2*)(xp + kt * 8 + q * 2));
        } else {
#pragma unroll
          for (int kt = 0; kt < 4; ++kt) {
            u64x2 t2;
            t2.x = lda(xp + kt * 8 + q * 2);
            t2.y = lda(xp + kt * 8 + q * 2 + 1);
            xf[kt] = __builtin_bit_cast(half8, t2);
          }
        }
      }

      // accX chain BEFORE the spin (depends only on xf)
      f32x4 accX = {b0v[0], b0v[1], b0v[2], b0v[3]};
#pragma unroll
      for (int kt = 0; kt < 4; ++kt) {
        accX = MFMA16(fX[kt], xf[kt], accX);
        accX = MFMA16(fXlo[kt], hscale(xf[kt]), accX);
      }

      if (r > 0) {
        // spin: own team's h0[r-1] ready AND L1 done with h0[r-4]
        // (writing slot r&3; flag1 >= r-3 <=> L1 published h1[r-4] and will
        // never again read any h0 older than h0[r-3])
        int guard = 0;
        for (;;) {
          u64 f0 = lda(s0p), f1 = lda(s1p);
          bool ok = ((int)(unsigned)f0 >= r) && ((int)(f0 >> 32) >= r) &&
                    ((int)(unsigned)f1 >= r - 3) && ((int)(f1 >> 32) >= r - 3);
          if (__ballot(ok) == ~0ull) break;
          if (++guard > 4096) break;  // diagnostic fail-fast, never hangs
        }
        asm volatile("" ::: "memory");  // keep staging below the spin
        // stage h0[r-1] (16KB) from slot (r-1)&3
        if (loc) {
          const u64x2* src =
              (const u64x2*)exch + ((size_t)((r - 1) & 3) * 8 + c) * 1024 + tid;
          u64x2 v[4];
#pragma unroll
          for (int i = 0; i < 4; ++i) v[i] = src[i * 256];
          u64x2* dst = (u64x2*)hbuf[0] + tid;
#pragma unroll
          for (int i = 0; i < 4; ++i) dst[i * 256] = v[i];
        } else {
          const u64* src =
              (const u64*)exch + ((size_t)((r - 1) & 3) * 8 + c) * 2048 + tid;
          u64 v[8];
#pragma unroll
          for (int i = 0; i < 8; ++i) v[i] = lda(src + i * 256);
          u64* dst = (u64*)hbuf[0] + tid;
#pragma unroll
          for (int i = 0; i < 8; ++i) dst[i * 256] = v[i];
        }
      }
      __syncthreads();

      f32x4 a0 = {0.f, 0.f, 0.f, 0.f};
      f32x4 a0b = a0, a0l = a0, a0bl = a0;
      if (r > 0) {
#pragma unroll
        for (int kt = 0; kt < 8; ++kt) {
          half8 hA = *(const half8*)(&hbuf[0][kt][q][bb][0]);
          half8 hB = *(const half8*)(&hbuf[0][kt + 8][q][bb][0]);
          a0 = MFMA16(fW0[kt], hA, a0);
          a0b = MFMA16(fW0[kt + 8], hB, a0b);
          a0l = MFMA16(fW0lo[kt], hscale(hA), a0l);
          a0bl = MFMA16(fW0lo[kt + 8], hscale(hB), a0bl);
        }
      }
      f32x4 g0 = accX + ((a0 + a0b) + (a0l + a0bl));
      float gi = sigf(g0.x), gf = sigf(g0.y), gg = tanhf_(g0.z),
            go = sigf(g0.w);
      c0 = gf * c0 + gi * gg;
      float h0v = go * tanhf_(c0);
      size_t hidx = ((size_t)(r & 3) * 8 + c) * 8192 + hoff;
      if (loc)
        exch[hidx] = f2h(h0v);  // plain -> dirty line in local L2
      else
        __hip_atomic_store(exch + hidx, f2h(h0v), __ATOMIC_RELAXED,
                           __HIP_MEMORY_SCOPE_AGENT);

      asm volatile("s_waitcnt vmcnt(0)" ::: "memory");  // h0 drained
      if (lane == 0) {
        if (loc)
          __hip_atomic_store(flag0 + wcl, (unsigned)(r + 1), __ATOMIC_RELAXED,
                             __HIP_MEMORY_SCOPE_WORKGROUP);
        else
          __hip_atomic_store(flag0 + wcl, (unsigned)(r + 1), __ATOMIC_RELAXED,
                             __HIP_MEMORY_SCOPE_AGENT);
      }

      // x refresh stores AFTER the flag (off every wave's convoy path;
      // consumed 32 rounds later, drained by next round's vmcnt(0))
      if (doref) {
#pragma unroll
        for (int j = 0; j < 4; ++j) {
          size_t xidx =
              (((size_t)(sw * 8 + c) * 32 + rw + j) * 16 + xb) * 128 + xd;
          if (loc)
            xtw16[xidx] = f2h(xv4[j]);
          else
            __hip_atomic_store(xtw16 + xidx, f2h(xv4[j]), __ATOMIC_RELAXED,
                               __HIP_MEMORY_SCOPE_AGENT);
        }
      }
    }
  } else {
    // ========= L1 team: layer 1, software-pipelined behind L0 =========
    half8 fW1i[16], fW1ilo[16], fW1h[16];
    {
      const float* p1 = Wih1 + (size_t)arow * 512 + q * 8;
      const float* p2 = Whh1 + (size_t)arow * 512 + q * 8;
#pragma unroll
      for (int kt = 0; kt < 16; ++kt) {
        f32x4 a1 = *(const f32x4*)(p1 + kt * 32),
              b1 = *(const f32x4*)(p1 + kt * 32 + 4);
        cvt_split(a1, b1, fW1i[kt], fW1ilo[kt]);
        f32x4 a2 = *(const f32x4*)(p2 + kt * 32),
              b2 = *(const f32x4*)(p2 + kt * 32 + 4);
        half8 dummy;
        cvt_split(a2, b2, fW1h[kt], dummy);  // hi only
      }
    }
    float b1v[4];
#pragma unroll
    for (int g = 0; g < 4; ++g) {
      int rrow = g * 512 + chbase + q;
      b1v[g] = bih1[rrow] + bhh1[rrow];
    }
    const float fcw0 = fcW[ch], fcw1 = fcW[512 + ch];

    float c1 = 0.f;
    f32x4 a1 = {b1v[0], b1v[1], b1v[2], b1v[3]};
    f32x4 a1b = {0.f, 0.f, 0.f, 0.f};

    // ---- prologue: a1_pre for t=0 (Wih1 * h0[0], parity buffer 1) ----
    {
      int guard = 0;
      for (;;) {
        u64 f0 = lda(s0p);
        bool ok = ((int)(unsigned)f0 >= 1) && ((int)(f0 >> 32) >= 1);
        if (__ballot(ok) == ~0ull) break;
        if (++guard > 8192) break;
      }
      asm volatile("" ::: "memory");
      if (loc) {
        const u64x2* src = (const u64x2*)exch + (size_t)c * 1024 + tid;
        u64x2 v[4];
#pragma unroll
        for (int i = 0; i < 4; ++i) v[i] = src[i * 256];
        u64x2* dst = (u64x2*)hbuf[1] + tid;
#pragma unroll
        for (int i = 0; i < 4; ++i) dst[i * 256] = v[i];
      } else {
        const u64* src = (const u64*)exch + (size_t)c * 2048 + tid;
        u64 v[8];
#pragma unroll
        for (int i = 0; i < 8; ++i) v[i] = lda(src + i * 256);
        u64* dst = (u64*)hbuf[1] + tid;
#pragma unroll
        for (int i = 0; i < 8; ++i) dst[i * 256] = v[i];
      }
      __syncthreads();
#pragma unroll
      for (int kt = 0; kt < 8; ++kt) {
        half8 hA = *(const half8*)(&hbuf[1][kt][q][bb][0]);
        half8 hB = *(const half8*)(&hbuf[1][kt + 8][q][bb][0]);
        a1 = MFMA16(fW1i[kt], hA, a1);
        a1b = MFMA16(fW1i[kt + 8], hB, a1b);
        a1 = MFMA16(fW1ilo[kt], hscale(hA), a1);
        a1b = MFMA16(fW1ilo[kt + 8], hscale(hB), a1b);
      }
    }

    for (int t = 0; t < T; ++t) {
      // ---- h1-recurrence segment (the only work between flag1 stores) ----
      if (t > 0) {
        int guard = 0;
        for (;;) {
          u64 f1 = lda(s1p);
          bool ok = ((int)(unsigned)f1 >= t) && ((int)(f1 >> 32) >= t);
          if (__ballot(ok) == ~0ull) break;
          if (++guard > 4096) break;
        }
        asm volatile("" ::: "memory");
        // stage h1[t-1] (16KB, parity (t-1)&1) into hbuf[0]
        if (loc) {
          const u64x2* src = (const u64x2*)exch1 +
                             ((size_t)((t - 1) & 1) * 8 + c) * 1024 + tid;
          u64x2 v[4];
#pragma unroll
          for (int i = 0; i < 4; ++i) v[i] = src[i * 256];
          u64x2* dst = (u64x2*)hbuf[0] + tid;
#pragma unroll
          for (int i = 0; i < 4; ++i) dst[i * 256] = v[i];
        } else {
          const u64* src =
              (const u64*)exch1 + ((size_t)((t - 1) & 1) * 8 + c) * 2048 + tid;
          u64 v[8];
#pragma unroll
          for (int i = 0; i < 8; ++i) v[i] = lda(src + i * 256);
          u64* dst = (u64*)hbuf[0] + tid;
#pragma unroll
          for (int i = 0; i < 8; ++i) dst[i * 256] = v[i];
        }
      }
      __syncthreads();

      f32x4 a1c = {0.f, 0.f, 0.f, 0.f};
      f32x4 a1d = a1c;
      if (t > 0) {
#pragma unroll
        for (int kt = 0; kt < 8; ++kt) {
          half8 hC = *(const half8*)(&hbuf[0][kt][q][bb][0]);
          half8 hD = *(const half8*)(&hbuf[0][kt + 8][q][bb][0]);
          a1c = MFMA16(fW1h[kt], hC, a1c);
          a1d = MFMA16(fW1h[kt + 8], hD, a1d);
        }
      }
      f32x4 g1 = (a1 + a1b) + (a1c + a1d);
      float gi = sigf(g1.x), gf = sigf(g1.y), gg = tanhf_(g1.z),
            go = sigf(g1.w);
      c1 = gf * c1 + gi * gg;
      float h1v = go * tanhf_(c1);

      if (t == T - 1) {
        // fc head (out zeroed by prep_kernel each call)
        float s0 = h1v * fcw0, s1 = h1v * fcw1;
        s0 += __shfl_xor(s0, 16); s0 += __shfl_xor(s0, 32);
        s1 += __shfl_xor(s1, 16); s1 += __shfl_xor(s1, 32);
        if (q == 0) {
          atomicAdd(out + (size_t)(c * 16 + bb) * 2 + 0, s0);
          atomicAdd(out + (size_t)(c * 16 + bb) * 2 + 1, s1);
        }
        if (wcl == 0 && lane < 32)
          atomicAdd(out + (size_t)(c * 16 + (lane & 15)) * 2 + (lane >> 4),
                    fcb[lane >> 4]);
      } else {
        size_t hidx = ((size_t)(t & 1) * 8 + c) * 8192 + hoff;
        if (loc)
          exch1[hidx] = f2h(h1v);
        else
          __hip_atomic_store(exch1 + hidx, f2h(h1v), __ATOMIC_RELAXED,
                             __HIP_MEMORY_SCOPE_AGENT);
      }
      asm volatile("s_waitcnt vmcnt(0)" ::: "memory");  // h1 drained
      if (lane == 0) {
        if (loc)
          __hip_atomic_store(flag1 + wcl, (unsigned)(t + 1), __ATOMIC_RELAXED,
                             __HIP_MEMORY_SCOPE_WORKGROUP);
        else
          __hip_atomic_store(flag1 + wcl, (unsigned)(t + 1), __ATOMIC_RELAXED,
                             __HIP_MEMORY_SCOPE_AGENT);
      }

      // ---- tail: prefetch h0[t+1] + Wih1 chain for next round (off the
      //      flag1->flag1 serial path; h0[t+1] available via L0's lead) ----
      if (t < T - 1) {
        int guard = 0;
        for (;;) {
          u64 f0 = lda(s0p);
          bool ok = ((int)(unsigned)f0 >= t + 2) && ((int)(f0 >> 32) >= t + 2);
          if (__ballot(ok) == ~0ull) break;
          if (++guard > 4096) break;
        }
        asm volatile("" ::: "memory");
        const int buf = 1 + ((t + 1) & 1);
        if (loc) {
          const u64x2* src = (const u64x2*)exch +
                             ((size_t)((t + 1) & 3) * 8 + c) * 1024 + tid;
          u64x2 v[4];
#pragma unroll
          for (int i = 0; i < 4; ++i) v[i] = src[i * 256];
          u64x2* dst = (u64x2*)hbuf[buf] + tid;
#pragma unroll
          for (int i = 0; i < 4; ++i) dst[i * 256] = v[i];
        } else {
          const u64* src =
              (const u64*)exch + ((size_t)((t + 1) & 3) * 8 + c) * 2048 + tid;
          u64 v[8];
#pragma unroll
          for (int i = 0; i < 8; ++i) v[i] = lda(src + i * 256);
          u64* dst = (u64*)hbuf[buf] + tid;
#pragma unroll
          for (int i = 0; i < 8; ++i) dst[i * 256] = v[i];
        }
        __syncthreads();
        a1 = {b1v[0], b1v[1], b1v[2], b1v[3]};
        a1b = {0.f, 0.f, 0.f, 0.f};
#pragma unroll
        for (int kt = 0; kt < 8; ++kt) {
          half8 hA = *(const half8*)(&hbuf[buf][kt][q][bb][0]);
          half8 hB = *(const half8*)(&hbuf[buf][kt + 8][q][bb][0]);
          a1 = MFMA16(fW1i[kt], hA, a1);
          a1b = MFMA16(fW1i[kt + 8], hB, a1b);
          a1 = MFMA16(fW1ilo[kt], hscale(hA), a1);
          a1b = MFMA16(fW1ilo[kt + 8], hscale(hB), a1b);
        }
      }
    }
  }
}

extern "C" void kernel_launch(void* const* d_in, const int* in_sizes, int n_in,
                              void* d_out, int out_size, void* d_ws,
                              size_t ws_size, hipStream_t stream) {
  const float* x = (const float*)d_in[0];
  const float* Wih0 = (const float*)d_in[1];
  const float* Whh0 = (const float*)d_in[2];
  const float* bih0 = (const float*)d_in[3];
  const float* bhh0 = (const float*)d_in[4];
  const float* Wih1 = (const float*)d_in[5];
  const float* Whh1 = (const float*)d_in[6];
  const float* bih1 = (const float*)d_in[7];
  const float* bhh1 = (const float*)d_in[8];
  const float* fcW = (const float*)d_in[9];
  const float* fcb = (const float*)d_in[10];

  char* ws = (char*)d_ws;  // uses < 4MB total
  unsigned* sync = (unsigned*)ws;
  unsigned short* exch = (unsigned short*)(ws + WS_H0_OFF);
  _Float16* xTw = (_Float16*)(ws + WS_XTW_OFF);
  float* out = (float*)d_out;

  prep_kernel<<<dim3(128), dim3(256), 0, stream>>>(x, xTw, sync, out);
  lstm_scan<<<dim3(512), dim3(256), 0, stream>>>(Whh0, bih0, bhh0, Wih1, Whh1,
                                                 bih1, bhh1, fcW, fcb, Wih0, x,
                                                 sync, exch, xTw, out);
}